// Round 13
// baseline (829.324 us; speedup 1.0000x reference)
//
#include <hip/hip_runtime.h>
#include <hip/hip_bf16.h>

#define B_  32
#define N_  512
#define D_  256
#define H_  8
#define HD_ 32
#define LW_ 25

typedef __hip_bfloat16 bf;
typedef __attribute__((ext_vector_type(8))) short short8;
typedef __attribute__((ext_vector_type(4))) float f32x4;

__device__ __forceinline__ void gload16(const void* g, void* l) {
    __builtin_amdgcn_global_load_lds(
        (const __attribute__((address_space(1))) unsigned int*)g,
        (__attribute__((address_space(3))) unsigned int*)l, 16, 0, 0);
}

// 1/sqrt(32) * log2(e): folded into Q so attention uses raw exp2
#define QSC 0.2550349f

// ---------------------------------------------------------------------------
// MFMA bf16 GEMM (LDS-staged, 128x128 tile): used ONLY for the splitK
// skill-table GEMM (K=2048, atomics) where the big tile amortizes best.
// flags: 1=relu, 2=accumulate into Cf, 4=atomicAdd (splitK).
// ---------------------------------------------------------------------------
__global__ __launch_bounds__(256) void gemm2_k(
    const bf* Aq, const bf* Akv, const bf* W, const float* bias,
    float* Cf, bf* Cb, float* Cacc,
    int M, int K, int Onum,
    int rowsPerA, long long aBatch, int aRstride, long long aKMul,
    long long aZ, long long wZ, long long cZ,
    int qkvmode, int flags, int splitKc,
    bf* Qd, bf* Kd, bf* Vd, int Lseq, int Lvt)
{
    __shared__ __align__(16) bf As[128 * 32];
    __shared__ __align__(16) bf Bs[128 * 32];
    const int tid = threadIdx.x;
    const int o0 = blockIdx.x * 128;
    const int m0 = blockIdx.y * 128;
    const int z  = blockIdx.z;
    const bf* A = (qkvmode && o0 >= 256) ? Akv : Aq;
    const bf* Wp = W;
    int kStart = 0, kEnd = K;
    if (splitKc > 0) {
        kStart = z * splitKc;
        kEnd   = min(K, kStart + splitKc);
    } else {
        A  += (long long)z * aZ;
        Wp += (long long)z * wZ;
        if (Cf) Cf += (long long)z * cZ;
        if (Cb) Cb += (long long)z * cZ;
    }

    const int w = tid >> 6, lane = tid & 63;
    const int col = lane & 15, quad = lane >> 4;
    const int wm = (w & 1) * 64;
    const int wn = (w >> 1) * 64;

    const int sidx0 = tid, sidx1 = tid + 256;
    long long arow0, arow1;
    {
        int m = m0 + (sidx0 >> 2);
        arow0 = (long long)(m / rowsPerA) * aBatch + (long long)(m % rowsPerA) * aRstride;
        m = m0 + (sidx1 >> 2);
        arow1 = (long long)(m / rowsPerA) * aBatch + (long long)(m % rowsPerA) * aRstride;
    }
    const long long wrow0 = (long long)(o0 + (sidx0 >> 2)) * K;
    const long long wrow1 = (long long)(o0 + (sidx1 >> 2)) * K;
    const int ac0 = (sidx0 & 3) * 8, ac1 = (sidx1 & 3) * 8;

    f32x4 acc[4][4];
    #pragma unroll
    for (int mt = 0; mt < 4; mt++)
        #pragma unroll
        for (int nt = 0; nt < 4; nt++)
            acc[mt][nt] = (f32x4)0.f;

    for (int k0 = kStart; k0 < kEnd; k0 += 32) {
        const long long ka = (long long)k0 * aKMul;
        gload16(A + arow0 + ka + ac0, As + sidx0 * 8);
        gload16(A + arow1 + ka + ac1, As + sidx1 * 8);
        gload16(Wp + wrow0 + k0 + ac0, Bs + sidx0 * 8);
        gload16(Wp + wrow1 + k0 + ac1, Bs + sidx1 * 8);
        __syncthreads();
        short8 af[4], bfr[4];
        #pragma unroll
        for (int mt = 0; mt < 4; mt++)
            af[mt] = *(const short8*)(As + (wm + mt * 16 + col) * 32 + quad * 8);
        #pragma unroll
        for (int nt = 0; nt < 4; nt++)
            bfr[nt] = *(const short8*)(Bs + (wn + nt * 16 + col) * 32 + quad * 8);
        #pragma unroll
        for (int mt = 0; mt < 4; mt++)
            #pragma unroll
            for (int nt = 0; nt < 4; nt++)
                acc[mt][nt] = __builtin_amdgcn_mfma_f32_16x16x32_bf16(
                    af[mt], bfr[nt], acc[mt][nt], 0, 0, 0);
        __syncthreads();
    }

    #pragma unroll
    for (int mt = 0; mt < 4; mt++) {
        #pragma unroll
        for (int nt = 0; nt < 4; nt++) {
            const int o = o0 + wn + nt * 16 + col;
            #pragma unroll
            for (int r = 0; r < 4; r++) {
                const int m = m0 + wm + mt * 16 + quad * 4 + r;
                if (m >= M) continue;
                float v = acc[mt][nt][r];
                if (bias) v += bias[o];
                if (flags & 1) v = fmaxf(v, 0.f);
                if (flags & 4) {
                    atomicAdd(Cf + (long long)m * Onum + o, v);
                } else {
                    long long ci = (long long)m * Onum + o;
                    if (flags & 2) v += Cf[ci];
                    if (Cf) Cf[ci] = v;
                    if (Cb) Cb[ci] = __float2bfloat16(v);
                    if (Cacc) Cacc[ci] += v;
                }
            }
        }
    }
}

// ---------------------------------------------------------------------------
// MFMA bf16 GEMM (LDS-staged, 64x64 tile): kept for odd shapes (attn1-out
// M=800, batched BNN O=512, stew K=512). 4 waves x (32x32).
// ---------------------------------------------------------------------------
__global__ __launch_bounds__(256) void gemm64_k(
    const bf* A, const bf* W, const float* bias,
    float* Cf, bf* Cb, float* Cacc,
    int M, int K, int Onum,
    int rowsPerA, long long aBatch, int aRstride, long long aKMul,
    long long aZ, long long wZ, long long cZ, int flags)
{
    __shared__ __align__(16) bf As[64 * 32];
    __shared__ __align__(16) bf Bs[64 * 32];
    const int tid = threadIdx.x;
    const int o0 = blockIdx.x * 64;
    const int m0 = blockIdx.y * 64;
    const int z  = blockIdx.z;
    A += (long long)z * aZ;
    W += (long long)z * wZ;
    if (Cf)   Cf   += (long long)z * cZ;
    if (Cb)   Cb   += (long long)z * cZ;
    if (Cacc) Cacc += (long long)z * cZ;

    const int w = tid >> 6, lane = tid & 63;
    const int col = lane & 15, quad = lane >> 4;
    const int wm = (w & 1) * 32;
    const int wn = (w >> 1) * 32;

    const int srow = tid >> 2;          // 0..63
    const int sac  = (tid & 3) * 8;
    long long arow;
    {
        const int m = m0 + srow;
        arow = (long long)(m / rowsPerA) * aBatch
             + (long long)(m % rowsPerA) * aRstride;
    }
    const long long wrow = (long long)(o0 + srow) * K;

    f32x4 acc[2][2];
    acc[0][0] = (f32x4)0.f; acc[0][1] = (f32x4)0.f;
    acc[1][0] = (f32x4)0.f; acc[1][1] = (f32x4)0.f;

    for (int k0 = 0; k0 < K; k0 += 32) {
        gload16(A + arow + (long long)k0 * aKMul + sac, As + tid * 8);
        gload16(W + wrow + k0 + sac, Bs + tid * 8);
        __syncthreads();
        short8 af[2], bfr[2];
        #pragma unroll
        for (int mt = 0; mt < 2; mt++)
            af[mt] = *(const short8*)(As + (wm + mt * 16 + col) * 32 + quad * 8);
        #pragma unroll
        for (int nt = 0; nt < 2; nt++)
            bfr[nt] = *(const short8*)(Bs + (wn + nt * 16 + col) * 32 + quad * 8);
        #pragma unroll
        for (int mt = 0; mt < 2; mt++)
            #pragma unroll
            for (int nt = 0; nt < 2; nt++)
                acc[mt][nt] = __builtin_amdgcn_mfma_f32_16x16x32_bf16(
                    af[mt], bfr[nt], acc[mt][nt], 0, 0, 0);
        __syncthreads();
    }

    #pragma unroll
    for (int mt = 0; mt < 2; mt++) {
        #pragma unroll
        for (int nt = 0; nt < 2; nt++) {
            const int o = o0 + wn + nt * 16 + col;
            #pragma unroll
            for (int r = 0; r < 4; r++) {
                const int m = m0 + wm + mt * 16 + quad * 4 + r;
                if (m >= M) continue;
                float v = acc[mt][nt][r];
                if (bias) v += bias[o];
                if (flags & 1) v = fmaxf(v, 0.f);
                if (flags & 4) {
                    atomicAdd(Cf + (long long)m * Onum + o, v);
                } else {
                    long long ci = (long long)m * Onum + o;
                    if (flags & 2) v += Cf[ci];
                    if (Cf) Cf[ci] = v;
                    if (Cb) Cb[ci] = __float2bfloat16(v);
                    if (Cacc) Cacc[ci] += v;
                }
            }
        }
    }
}

// ---------------------------------------------------------------------------
// Epilogue GEMM (dgemm-v3 structure): K=KC*32 compile-time, O multiple of 64.
// W tile (64o x K) staged ONCE into padded LDS; ALL A fragments issued
// up-front so global latency hides under staging + barrier; K-loop is pure
// regs+LDS (no barriers, no global latency on critical path). XCD-grouped
// o-blocks (bijective when nmb%8==0). Generalized A addressing + gemm64
// epilogue (flags 1=relu, 2=acc-from-Cf; Cf/Cb/Cacc optional).
// Block = 128m x 64o, 4 waves on m.
// ---------------------------------------------------------------------------
template<int KC>
__global__ __launch_bounds__(256) void egemm_k(
    const bf* A, const bf* W, const float* bias,
    float* Cf, bf* Cb, float* Cacc,
    int M, int Onum,
    int rowsPerA, long long aBatch, int aRstride, long long aKMul,
    int flags)
{
    __shared__ __align__(16) bf Ws[64][264];   // padded: row stride 528B
    const int tid = threadIdx.x;
    const int w = tid >> 6, lane = tid & 63;
    const int col = lane & 15, quad = lane >> 4;
    const int OB = Onum >> 6;
    const int nmb = gridDim.x / OB;
    int ob, mb;
    if ((nmb & 7) == 0) {
        const int xcd = blockIdx.x & 7;
        const int q = blockIdx.x >> 3;
        mb = xcd + 8 * (q / OB);
        ob = q % OB;
    } else {
        ob = blockIdx.x % OB;
        mb = blockIdx.x / OB;
    }
    const int o0 = ob * 64;
    const int m0 = mb * 128;
    const int K = KC * 32;

    const bf* aP[2];
    #pragma unroll
    for (int mt = 0; mt < 2; mt++) {
        const int m = m0 + w * 32 + mt * 16 + col;
        aP[mt] = A + (long long)(m / rowsPerA) * aBatch
               + (long long)(m % rowsPerA) * aRstride + quad * 8;
    }

    // ---- issue ALL A fragment loads (latency overlaps staging+barrier) ----
    short8 afr[2][KC];
    #pragma unroll
    for (int kc = 0; kc < KC; kc++) {
        afr[0][kc] = *(const short8*)(aP[0] + (long long)kc * 32 * aKMul);
        afr[1][kc] = *(const short8*)(aP[1] + (long long)kc * 32 * aKMul);
    }

    // ---- stage W tile into padded LDS (coalesced 512B rows) ----
    {
        const int srow = tid >> 5;          // 0..7
        const int sk   = (tid & 31) * 8;    // 0..248
        #pragma unroll
        for (int rd = 0; rd < 8; rd++) {
            const int row = rd * 8 + srow;
            const short8 wv = *(const short8*)(W + (long long)(o0 + row) * K + sk);
            *(short8*)(&Ws[row][sk]) = wv;
        }
    }
    __syncthreads();

    f32x4 acc[2][4];
    #pragma unroll
    for (int mt = 0; mt < 2; mt++)
        #pragma unroll
        for (int ot = 0; ot < 4; ot++)
            acc[mt][ot] = (f32x4)0.f;

    #pragma unroll
    for (int kc = 0; kc < KC; kc++) {
        #pragma unroll
        for (int ot = 0; ot < 4; ot++) {
            const short8 bfg = *(const short8*)(&Ws[ot * 16 + col][kc * 32 + quad * 8]);
            acc[0][ot] = __builtin_amdgcn_mfma_f32_16x16x32_bf16(
                afr[0][kc], bfg, acc[0][ot], 0, 0, 0);
            acc[1][ot] = __builtin_amdgcn_mfma_f32_16x16x32_bf16(
                afr[1][kc], bfg, acc[1][ot], 0, 0, 0);
        }
    }

    #pragma unroll
    for (int mt = 0; mt < 2; mt++) {
        #pragma unroll
        for (int ot = 0; ot < 4; ot++) {
            const int o = o0 + ot * 16 + col;
            #pragma unroll
            for (int r = 0; r < 4; r++) {
                const int m = m0 + w * 32 + mt * 16 + quad * 4 + r;
                if (m >= M) continue;
                float v = acc[mt][ot][r];
                if (bias) v += bias[o];
                if (flags & 1) v = fmaxf(v, 0.f);
                long long ci = (long long)m * Onum + o;
                if (flags & 2) v += Cf[ci];
                if (Cf) Cf[ci] = v;
                if (Cb) Cb[ci] = __float2bfloat16(v);
                if (Cacc) Cacc[ci] += v;
            }
        }
    }
}

// ---------------------------------------------------------------------------
// QKV GEMM v3: W tile staged once into padded LDS; all A fragments issued
// up-front. XCD-aware 1-D grid decode. LP2>0: pow2 Lseq => shift/mask
// addressing, V^T stores packed as 8B ushort4. Block = 128m x 64o.
// ---------------------------------------------------------------------------
template<int LP2, int KC>
__global__ __launch_bounds__(256) void dgemm_k(
    const bf* Aq, const bf* Akv, const bf* W, const float* bias,
    int M,
    int rowsPerA, long long aBatch, int aRstride, long long aKMul,
    bf* Qd, bf* Kd, bf* Vd, int Lseq, int Lvt)
{
    __shared__ __align__(16) bf Ws[64][264];   // padded: row stride 528B
    const int tid = threadIdx.x;
    const int w = tid >> 6, lane = tid & 63;
    const int col = lane & 15, quad = lane >> 4;
    const int nmb = gridDim.x / 12;
    int ob, mb;
    if ((nmb & 7) == 0) {
        const int xcd = blockIdx.x & 7;
        const int q = blockIdx.x >> 3;
        mb = xcd + 8 * (q / 12);
        ob = q % 12;
    } else {
        ob = blockIdx.x % 12;
        mb = blockIdx.x / 12;
    }
    const int o0 = ob * 64;
    const int m0 = mb * 128;
    const bf* A = (o0 >= 256) ? Akv : Aq;
    const int K = KC * 32;

    const bf* aP[2];
    #pragma unroll
    for (int mt = 0; mt < 2; mt++) {
        const int m = m0 + w * 32 + mt * 16 + col;
        aP[mt] = A + (long long)(m / rowsPerA) * aBatch
               + (long long)(m % rowsPerA) * aRstride + quad * 8;
    }

    // ---- issue ALL A fragment loads (latency overlaps staging+barrier) ----
    short8 afr[2][KC];
    #pragma unroll
    for (int kc = 0; kc < KC; kc++) {
        afr[0][kc] = *(const short8*)(aP[0] + (long long)kc * 32 * aKMul);
        afr[1][kc] = *(const short8*)(aP[1] + (long long)kc * 32 * aKMul);
    }

    // ---- stage W tile into padded LDS (coalesced 512B rows) ----
    {
        const int srow = tid >> 5;          // 0..7
        const int sk   = (tid & 31) * 8;    // 0..248
        #pragma unroll
        for (int rd = 0; rd < 8; rd++) {
            const int row = rd * 8 + srow;
            const short8 wv = *(const short8*)(W + (long long)(o0 + row) * K + sk);
            *(short8*)(&Ws[row][sk]) = wv;
        }
    }
    __syncthreads();

    f32x4 acc[2][4];
    #pragma unroll
    for (int mt = 0; mt < 2; mt++)
        #pragma unroll
        for (int ot = 0; ot < 4; ot++)
            acc[mt][ot] = (f32x4)0.f;

    #pragma unroll
    for (int kc = 0; kc < KC; kc++) {
        #pragma unroll
        for (int ot = 0; ot < 4; ot++) {
            const short8 bfg = *(const short8*)(&Ws[ot * 16 + col][kc * 32 + quad * 8]);
            acc[0][ot] = __builtin_amdgcn_mfma_f32_16x16x32_bf16(
                afr[0][kc], bfg, acc[0][ot], 0, 0, 0);
            acc[1][ot] = __builtin_amdgcn_mfma_f32_16x16x32_bf16(
                afr[1][kc], bfg, acc[1][ot], 0, 0, 0);
        }
    }

    const int which = o0 >> 8;   // block-uniform: 0=Q, 1=K, 2=V
    #pragma unroll
    for (int mt = 0; mt < 2; mt++) {
        const int mb4 = m0 + w * 32 + mt * 16 + quad * 4;
        #pragma unroll
        for (int ot = 0; ot < 4; ot++) {
            const int o  = o0 + ot * 16 + col;
            const int j2 = o & 31;
            const int hh = (o >> 5) & 7;
            if (LP2 > 0) {
                const int bb  = mb4 >> LP2;
                const int nn0 = mb4 & ((1 << LP2) - 1);
                const int bh  = bb * H_ + hh;
                float v0 = acc[mt][ot][0], v1 = acc[mt][ot][1],
                      v2 = acc[mt][ot][2], v3 = acc[mt][ot][3];
                if (bias) {
                    const float bv = bias[o];
                    v0 += bv; v1 += bv; v2 += bv; v3 += bv;
                }
                if (which == 0) {
                    bf* q = Qd + ((size_t)bh * Lseq + nn0) * HD_ + j2;
                    q[0]      = __float2bfloat16(v0 * QSC);
                    q[HD_]    = __float2bfloat16(v1 * QSC);
                    q[2*HD_]  = __float2bfloat16(v2 * QSC);
                    q[3*HD_]  = __float2bfloat16(v3 * QSC);
                } else if (which == 1) {
                    bf* kd = Kd + ((size_t)bh * Lseq + nn0) * HD_ + j2;
                    kd[0]     = __float2bfloat16(v0);
                    kd[HD_]   = __float2bfloat16(v1);
                    kd[2*HD_] = __float2bfloat16(v2);
                    kd[3*HD_] = __float2bfloat16(v3);
                } else {
                    __align__(8) bf pk[4];
                    pk[0] = __float2bfloat16(v0);
                    pk[1] = __float2bfloat16(v1);
                    pk[2] = __float2bfloat16(v2);
                    pk[3] = __float2bfloat16(v3);
                    *(ushort4*)(Vd + ((size_t)bh * HD_ + j2) * Lvt + nn0) =
                        *(const ushort4*)pk;
                }
            } else {
                #pragma unroll
                for (int r = 0; r < 4; r++) {
                    const int m = mb4 + r;
                    if (m >= M) continue;
                    float v = acc[mt][ot][r];
                    if (bias) v += bias[o];
                    const int bb = m / Lseq, nn = m % Lseq;
                    const int bh = bb * H_ + hh;
                    if (which == 0) {
                        Qd[((size_t)bh * Lseq + nn) * HD_ + j2] =
                            __float2bfloat16(v * QSC);
                    } else if (which == 1) {
                        Kd[((size_t)bh * Lseq + nn) * HD_ + j2] = __float2bfloat16(v);
                    } else {
                        Vd[((size_t)bh * HD_ + j2) * Lvt + nn] = __float2bfloat16(v);
                    }
                }
            }
        }
    }
}

// ---------------------------------------------------------------------------
// Per-wave flash attention v4 (64-key chunks): deferred-max + deferred-
// denominator; single-buffer P bounce (wave-private in-order DS); fixed
// per-iteration costs amortized over 2x keys; 4 QK + 4 PV MFMAs/iter.
// K fragments 1-deep rotation prefetch; V loaded at iteration top.
// Peeled chunk 0 (direct m init) and chunk cmax (causal mask, compile-time).
// Causal grids use reversed blockIdx.y (LPT). Requires L % 64 == 0, L >= 128.
// Grid: x = bh, y = q-supertile of 64 rows (4 waves x 16 rows).
// ---------------------------------------------------------------------------
template<int CAUSAL, int STATS>
__global__ __launch_bounds__(256) void fattn_k(
    const bf* __restrict__ Qb, const bf* __restrict__ Kb,
    const bf* __restrict__ Vtb, bf* __restrict__ O,
    float2* __restrict__ St, int L, int Lvt)
{
    __shared__ __align__(16) bf Sh[4][16][72];   // 64 keys + 8 pad (144B rows)
    const int tid = threadIdx.x;
    const int w = tid >> 6, lane = tid & 63;
    const int col = lane & 15, quad = lane >> 4;
    const int bh = blockIdx.x;
    const int yt = CAUSAL ? (int)(gridDim.y - 1 - blockIdx.y) : (int)blockIdx.y;
    const int q0 = yt * 64 + w * 16;
    const int NC = L >> 6;                        // 64-key chunks
    const int cmax = CAUSAL ? min(NC - 1, (q0 + 15) >> 6) : (NC - 1);

    const bf* Qh = Qb  + (size_t)bh * L * HD_;
    const bf* Kh = Kb  + (size_t)bh * L * HD_;
    const bf* Vh = Vtb + (size_t)bh * HD_ * Lvt;

    const short8 aq = *(const short8*)(Qh + (size_t)(q0 + col) * HD_ + quad * 8);

    float m[4];
    float sdp[4] = {0.f, 0.f, 0.f, 0.f};
    f32x4 oacc[2];
    oacc[0] = (f32x4)0.f; oacc[1] = (f32x4)0.f;

    const int qrow = q0 + quad * 4;
    const int kF = 16 * HD_;                      // 16-key stride in K
    const int vHf = 16 * Lvt;                     // hf=1 offset in V^T

    // pointer-stepped streams
    const bf* kP = Kh + (size_t)col * HD_ + quad * 8;   // chunk base (64 keys)
    const bf* vP = Vh + (size_t)col * Lvt + quad * 8;

    // core of one 64-key chunk (fragments already in regs; first/domask are
    // compile-time-foldable per call site)
    auto core = [&](const short8* kf, int c, bool domask, bool first) {
        f32x4 s[4];
        #pragma unroll
        for (int fi = 0; fi < 4; fi++)
            s[fi] = __builtin_amdgcn_mfma_f32_16x16x32_bf16(
                aq, kf[fi], (f32x4)0.f, 0, 0, 0);
        // V fragments: keys kh*32+quad*8, out-dims hf*16+col
        short8 vf00 = *(const short8*)(vP + (long long)c * 64);
        short8 vf01 = *(const short8*)(vP + (long long)c * 64 + vHf);
        short8 vf10 = *(const short8*)(vP + (long long)c * 64 + 32);
        short8 vf11 = *(const short8*)(vP + (long long)c * 64 + 32 + vHf);
        if (domask) {
            #pragma unroll
            for (int fi = 0; fi < 4; fi++) {
                const int key = c * 64 + fi * 16 + col;
                #pragma unroll
                for (int r = 0; r < 4; r++)
                    if (key > qrow + r) s[fi][r] = -1e9f;
            }
        }
        float pml[4];
        #pragma unroll
        for (int r = 0; r < 4; r++)
            pml[r] = fmaxf(fmaxf(s[0][r], s[1][r]), fmaxf(s[2][r], s[3][r]));
        if (first) {
            #pragma unroll
            for (int r = 0; r < 4; r++) {
                float pm = pml[r];
                #pragma unroll
                for (int off = 1; off < 16; off <<= 1)
                    pm = fmaxf(pm, __shfl_xor(pm, off));
                m[r] = pm;
            }
        } else {
            const int okr = (pml[0] <= m[0] + 8.f) && (pml[1] <= m[1] + 8.f)
                         && (pml[2] <= m[2] + 8.f) && (pml[3] <= m[3] + 8.f);
            if (!__all(okr)) {
                #pragma unroll
                for (int r = 0; r < 4; r++) {
                    float pm = pml[r];
                    #pragma unroll
                    for (int off = 1; off < 16; off <<= 1)
                        pm = fmaxf(pm, __shfl_xor(pm, off));
                    const float mn = fmaxf(m[r], pm);
                    const float scl = __builtin_amdgcn_exp2f(m[r] - mn);
                    m[r] = mn;
                    sdp[r] *= scl;
                    oacc[0][r] *= scl;
                    oacc[1][r] *= scl;
                }
            }
        }
        #pragma unroll
        for (int fi = 0; fi < 4; fi++)
            #pragma unroll
            for (int r = 0; r < 4; r++) {
                float e = __builtin_amdgcn_exp2f(s[fi][r] - m[r]);
                sdp[r] += e;
                Sh[w][quad * 4 + r][fi * 16 + col] = __float2bfloat16(e);
            }
        const short8 ap0 = *(const short8*)(&Sh[w][col][quad * 8]);
        const short8 ap1 = *(const short8*)(&Sh[w][col][32 + quad * 8]);
        oacc[0] = __builtin_amdgcn_mfma_f32_16x16x32_bf16(ap0, vf00, oacc[0], 0, 0, 0);
        oacc[0] = __builtin_amdgcn_mfma_f32_16x16x32_bf16(ap1, vf10, oacc[0], 0, 0, 0);
        oacc[1] = __builtin_amdgcn_mfma_f32_16x16x32_bf16(ap0, vf01, oacc[1], 0, 0, 0);
        oacc[1] = __builtin_amdgcn_mfma_f32_16x16x32_bf16(ap1, vf11, oacc[1], 0, 0, 0);
    };

    // preload K chunk 0 + chunk 1 (chunk 1 in-bounds: L >= 128)
    short8 kf[4], kn[4];
    #pragma unroll
    for (int fi = 0; fi < 4; fi++)
        kf[fi] = *(const short8*)(kP + fi * kF);
    kP += 64 * HD_;
    #pragma unroll
    for (int fi = 0; fi < 4; fi++)
        kn[fi] = *(const short8*)(kP + fi * kF);
    kP += 64 * HD_;

    // chunk 0 (peeled): direct m init; mask only when it's also the last
    core(kf, 0, CAUSAL && cmax == 0, true);
    #pragma unroll
    for (int fi = 0; fi < 4; fi++) kf[fi] = kn[fi];

    for (int c = 1; c < cmax; c++) {
        #pragma unroll
        for (int fi = 0; fi < 4; fi++)
            kn[fi] = *(const short8*)(kP + fi * kF);
        kP += 64 * HD_;
        core(kf, c, false, false);
        #pragma unroll
        for (int fi = 0; fi < 4; fi++) kf[fi] = kn[fi];
    }

    if (cmax >= 1)
        core(kf, cmax, CAUSAL != 0, false);

    // ---- final cross-lane denominator reduce (once) ----
    float inv[4];
    #pragma unroll
    for (int r = 0; r < 4; r++) {
        #pragma unroll
        for (int off = 1; off < 16; off <<= 1)
            sdp[r] += __shfl_xor(sdp[r], off);
        inv[r] = 1.f / sdp[r];
    }
    if (STATS && col == 0) {
        #pragma unroll
        for (int r = 0; r < 4; r++)
            St[(size_t)bh * L + q0 + quad * 4 + r] = make_float2(m[r], inv[r]);
    }
    #pragma unroll
    for (int hf = 0; hf < 2; hf++)
        #pragma unroll
        for (int r = 0; r < 4; r++)
            O[((size_t)bh * L + q0 + quad * 4 + r) * HD_ + hf * 16 + col] =
                __float2bfloat16(oacc[hf][r] * inv[r]);
}

// ---------------------------------------------------------------------------
// Head-mean attention probs for attn0 (causal): recompute QK^T per chunk,
// normalize with precomputed per-row (m, 1/sd) stats, accumulate mean over
// 8 heads in registers. No LDS, no barriers. Grid: x = b, y = 16-row q-tile.
// ---------------------------------------------------------------------------
__global__ __launch_bounds__(256) void meanp_k(
    const bf* __restrict__ Qb, const bf* __restrict__ Kb,
    const float2* __restrict__ St, float* __restrict__ meanW)
{
    const int tid = threadIdx.x;
    const int w = tid >> 6, lane = tid & 63;
    const int col = lane & 15, quad = lane >> 4;
    const int b = blockIdx.x;
    const int q0 = blockIdx.y * 16;
    const int cmax = (q0 + 15) >> 5;

    f32x4 mreg[4][2];
    #pragma unroll
    for (int cc = 0; cc < 4; cc++)
        #pragma unroll
        for (int hf = 0; hf < 2; hf++) mreg[cc][hf] = (f32x4)0.f;

    for (int h = 0; h < H_; h++) {
        const int bh = b * H_ + h;
        const bf* Qh = Qb + (size_t)bh * N_ * HD_;
        const bf* Kh = Kb + (size_t)bh * N_ * HD_;
        const short8 aq = *(const short8*)(Qh + (size_t)(q0 + col) * HD_ + quad * 8);
        float mrow[4], irow[4];
        #pragma unroll
        for (int r = 0; r < 4; r++) {
            float2 s2 = St[(size_t)bh * N_ + q0 + quad * 4 + r];
            mrow[r] = s2.x; irow[r] = s2.y;
        }
        #pragma unroll
        for (int cc = 0; cc < 4; cc++) {
            const int c = w + 4 * cc;
            if (c > cmax) continue;          // wave-uniform
            #pragma unroll
            for (int hf = 0; hf < 2; hf++) {
                const int key = c * 32 + hf * 16 + col;
                const short8 kf = *(const short8*)(Kh + (size_t)key * HD_ + quad * 8);
                f32x4 sc = __builtin_amdgcn_mfma_f32_16x16x32_bf16(
                    aq, kf, (f32x4)0.f, 0, 0, 0);
                #pragma unroll
                for (int r = 0; r < 4; r++) {
                    float p = (key > q0 + quad * 4 + r) ? 0.f
                        : __builtin_amdgcn_exp2f(sc[r] - mrow[r]) * irow[r];
                    mreg[cc][hf][r] += p;
                }
            }
        }
    }

    const size_t base = ((size_t)b * N_ + q0) * N_;
    #pragma unroll
    for (int cc = 0; cc < 4; cc++) {
        const int c = w + 4 * cc;
        #pragma unroll
        for (int hf = 0; hf < 2; hf++)
            #pragma unroll
            for (int r = 0; r < 4; r++)
                meanW[base + (size_t)(quad * 4 + r) * N_ + c * 32 + hf * 16 + col]
                    = mreg[cc][hf][r] * 0.125f;
    }
}

// ---------------------------------------------------------------------------
// MFMA attention v5 (kept for tiny local attn1):
// flash-style per-wave softmax + QT q-tiles per block.
// ---------------------------------------------------------------------------
#define SP 520
#define OPS 34

template<int MEAN, int QT>
__global__ __launch_bounds__(256) void attn5_k(
    const bf* Qb, const bf* Kb, const bf* Vtb,
    bf* O, float* meanW, int L, int Lvt, int causal, int nhl)
{
    __shared__ __align__(16) bf Sh[16 * SP];
    __shared__ __align__(16) float redm[2][16][4];
    __shared__ __align__(16) float invRow[16];
    __shared__ __align__(16) float Opart[4][16][OPS];
    const int tid = threadIdx.x;
    const int w = tid >> 6, lane = tid & 63;
    const int col = lane & 15, quad = lane >> 4;
    const int q0 = blockIdx.y * (16 * QT);
    const int bh0 = blockIdx.x * nhl;
    const int NCH = (L + 31) >> 5;
    const int qLast = q0 + (QT - 1) * 16;
    const int cmaxP = causal ? min(NCH - 1, (qLast + 15) >> 5) : (NCH - 1);
    const int nccP = (w <= cmaxP) ? ((cmaxP - w) >> 2) + 1 : 0;

    f32x4 mreg[4][2];
    if (MEAN) {
        #pragma unroll
        for (int cc = 0; cc < 4; cc++)
            #pragma unroll
            for (int hf = 0; hf < 2; hf++) mreg[cc][hf] = (f32x4)0.f;
    }

    for (int hh = 0; hh < nhl; hh++) {
        const int bh = bh0 + hh;
        const bf* Qh = Qb  + (size_t)bh * L * HD_;
        const bf* Kh = Kb  + (size_t)bh * L * HD_;
        const bf* Vh = Vtb + (size_t)bh * HD_ * Lvt;

        short8 aq[QT];
        #pragma unroll
        for (int t = 0; t < QT; t++) {
            aq[t] = (short8)(short)0;
            const int n = q0 + t * 16 + col;
            if (n < L)
                aq[t] = *(const short8*)(Qh + (size_t)n * HD_ + quad * 8);
        }
        short8 kfr[4][2], vfr[4][2];
        #pragma unroll
        for (int cc = 0; cc < 4; cc++) {
            if (cc >= nccP) break;
            const int c = w + 4 * cc;
            #pragma unroll
            for (int hf = 0; hf < 2; hf++) {
                const int key = c * 32 + hf * 16 + col;
                kfr[cc][hf] = (short8)(short)0;
                if (key < L)
                    kfr[cc][hf] = *(const short8*)(Kh + (size_t)key * HD_ + quad * 8);
                vfr[cc][hf] = *(const short8*)(Vh + (size_t)(hf * 16 + col) * Lvt
                                                + c * 32 + quad * 8);
            }
        }

        #pragma unroll
        for (int t = 0; t < QT; t++) {
            const int qt0 = q0 + t * 16;
            const int cmaxT = causal ? min(NCH - 1, (qt0 + 15) >> 5) : (NCH - 1);
            const int nccT = (w <= cmaxT) ? ((cmaxT - w) >> 2) + 1 : 0;

            f32x4 sc[4][2];
            #pragma unroll
            for (int cc = 0; cc < 4; cc++) {
                if (cc >= nccT) break;
                #pragma unroll
                for (int hf = 0; hf < 2; hf++)
                    sc[cc][hf] = __builtin_amdgcn_mfma_f32_16x16x32_bf16(
                        aq[t], kfr[cc][hf], (f32x4)0.f, 0, 0, 0);
            }

            float pm[4] = {-3e38f, -3e38f, -3e38f, -3e38f};
            #pragma unroll
            for (int cc = 0; cc < 4; cc++) {
                if (cc >= nccT) break;
                const int c = w + 4 * cc;
                #pragma unroll
                for (int hf = 0; hf < 2; hf++) {
                    const int key = c * 32 + hf * 16 + col;
                    #pragma unroll
                    for (int r = 0; r < 4; r++) {
                        float v = sc[cc][hf][r];
                        if (causal && key > qt0 + quad * 4 + r) v = -1e9f;
                        sc[cc][hf][r] = v;
                        pm[r] = fmaxf(pm[r], v);
                    }
                }
            }
            #pragma unroll
            for (int r = 0; r < 4; r++)
                #pragma unroll
                for (int off = 1; off < 16; off <<= 1)
                    pm[r] = fmaxf(pm[r], __shfl_xor(pm[r], off));

            float ps[4] = {0.f, 0.f, 0.f, 0.f};
            #pragma unroll
            for (int cc = 0; cc < 4; cc++) {
                if (cc >= nccT) break;
                const int c = w + 4 * cc;
                #pragma unroll
                for (int hf = 0; hf < 2; hf++)
                    #pragma unroll
                    for (int r = 0; r < 4; r++) {
                        float e = __builtin_amdgcn_exp2f(sc[cc][hf][r] - pm[r]);
                        sc[cc][hf][r] = e;
                        ps[r] += e;
                        Sh[(quad * 4 + r) * SP + c * 32 + hf * 16 + col] =
                            __float2bfloat16(e);
                    }
            }
            #pragma unroll
            for (int r = 0; r < 4; r++)
                #pragma unroll
                for (int off = 1; off < 16; off <<= 1)
                    ps[r] += __shfl_xor(ps[r], off);

            f32x4 oacc[2];
            oacc[0] = (f32x4)0.f; oacc[1] = (f32x4)0.f;
            #pragma unroll
            for (int cc = 0; cc < 4; cc++) {
                if (cc >= nccT) break;
                const int c = w + 4 * cc;
                const short8 ap = *(const short8*)(Sh + col * SP + c * 32 + quad * 8);
                #pragma unroll
                for (int hf = 0; hf < 2; hf++)
                    oacc[hf] = __builtin_amdgcn_mfma_f32_16x16x32_bf16(
                        ap, vfr[cc][hf], oacc[hf], 0, 0, 0);
            }

            if (col == 0) {
                #pragma unroll
                for (int r = 0; r < 4; r++) {
                    redm[0][quad * 4 + r][w] = pm[r];
                    redm[1][quad * 4 + r][w] = ps[r];
                }
            }
            __syncthreads();
            float esc[4], inv[4];
            #pragma unroll
            for (int r = 0; r < 4; r++) {
                f32x4 mw = *(const f32x4*)redm[0][quad * 4 + r];
                f32x4 sw = *(const f32x4*)redm[1][quad * 4 + r];
                float M = fmaxf(fmaxf(mw[0], mw[1]), fmaxf(mw[2], mw[3]));
                float T = sw[0] * __builtin_amdgcn_exp2f(mw[0] - M)
                        + sw[1] * __builtin_amdgcn_exp2f(mw[1] - M)
                        + sw[2] * __builtin_amdgcn_exp2f(mw[2] - M)
                        + sw[3] * __builtin_amdgcn_exp2f(mw[3] - M);
                esc[r] = __builtin_amdgcn_exp2f(pm[r] - M);
                inv[r] = 1.f / T;
            }
            if (w == 0 && col == 0) {
                #pragma unroll
                for (int r = 0; r < 4; r++) invRow[quad * 4 + r] = inv[r];
            }
            #pragma unroll
            for (int hf = 0; hf < 2; hf++)
                #pragma unroll
                for (int r = 0; r < 4; r++)
                    Opart[w][quad * 4 + r][hf * 16 + col] = oacc[hf][r] * esc[r];
            if (MEAN) {
                #pragma unroll
                for (int cc = 0; cc < 4; cc++) {
                    if (cc >= nccT) break;
                    #pragma unroll
                    for (int hf = 0; hf < 2; hf++)
                        #pragma unroll
                        for (int r = 0; r < 4; r++)
                            mreg[cc][hf][r] += sc[cc][hf][r] * (esc[r] * inv[r]);
                }
            }
            __syncthreads();

            for (int e = tid; e < 512; e += 256) {
                int row = e >> 5, d = e & 31;
                float v = (Opart[0][row][d] + Opart[1][row][d] +
                           Opart[2][row][d] + Opart[3][row][d]) * invRow[row];
                int n = qt0 + row;
                if (n < L)
                    O[((size_t)bh * L + n) * HD_ + d] = __float2bfloat16(v);
            }
            if (t + 1 < QT || hh + 1 < nhl) __syncthreads();
        }
    }

    if (MEAN) {
        const size_t base = ((size_t)blockIdx.x * N_ + q0) * N_;
        #pragma unroll
        for (int cc = 0; cc < 4; cc++) {
            const int c = w + 4 * cc;
            #pragma unroll
            for (int hf = 0; hf < 2; hf++)
                #pragma unroll
                for (int r = 0; r < 4; r++)
                    meanW[base + (size_t)(quad * 4 + r) * N_ + c * 32 + hf * 16 + col]
                        = mreg[cc][hf][r] * 0.125f;
        }
    }
}

// ---------------------------------------------------------------------------
// Small kernels
// ---------------------------------------------------------------------------
__global__ void conv_k(const float* s, bf* d, int n) {
    int i = blockIdx.x * 256 + threadIdx.x;
    if (i < n) d[i] = __float2bfloat16(s[i]);
}

__global__ __launch_bounds__(256) void rowsoftmax_k(const float* in, bf* out) {
    __shared__ float red[256];
    const long long row = blockIdx.x;
    const int t = threadIdx.x;
    const float* ip = in + row * 2048;
    bf* op = out + row * 2048;
    float m = -3e38f;
    for (int k = t; k < 2048; k += 256) m = fmaxf(m, ip[k]);
    red[t] = m; __syncthreads();
    for (int s = 128; s > 0; s >>= 1) { if (t < s) red[t] = fmaxf(red[t], red[t + s]); __syncthreads(); }
    m = red[0]; __syncthreads();
    float ps = 0.f;
    float ev[8];
    #pragma unroll
    for (int i = 0; i < 8; i++) { ev[i] = __expf(ip[t + i * 256] - m); ps += ev[i]; }
    red[t] = ps; __syncthreads();
    for (int s = 128; s > 0; s >>= 1) { if (t < s) red[t] += red[t + s]; __syncthreads(); }
    const float inv = 1.f / red[0];
    #pragma unroll
    for (int i = 0; i < 8; i++) op[t + i * 256] = __float2bfloat16(ev[i] * inv);
}

__global__ void embed_k(const int* q, const int* r, const int* qry,
                        const float* Memb, const float* Eemb, const float* P,
                        float* M, float* E, bf* Mh, bf* Eh) {
    const int i = blockIdx.x; const int t = threadIdx.x;
    const int n = i & (N_ - 1);
    const int x = q[i] + 2048 * r[i];
    float mv = Memb[(long long)x * D_ + t] + P[(long long)n * D_ + t];
    float evv = Eemb[(long long)qry[i] * D_ + t];
    M[(long long)i * D_ + t] = mv;  Mh[(long long)i * D_ + t] = __float2bfloat16(mv);
    E[(long long)i * D_ + t] = evv; Eh[(long long)i * D_ + t] = __float2bfloat16(evv);
}

__global__ void gather_k(const int* q, const float* T, const float* spb, bf* G) {
    const int i = blockIdx.x; const int t = threadIdx.x;
    G[(long long)i * D_ + t] = __float2bfloat16(T[(long long)q[i] * D_ + t] + spb[t]);
}

__global__ __launch_bounds__(256) void ln_k(const float* xa, const float* xb, const float* xc,
                                            const float* g, const float* bta,
                                            float* outF, bf* outB, float* out2) {
    __shared__ float red[256];
    const long long row = blockIdx.x;
    const int t = threadIdx.x;
    float v = xa[row * D_ + t];
    if (xb) v += xb[row * D_ + t];
    if (xc) v += xc[row * D_ + t];
    red[t] = v; __syncthreads();
    for (int s = 128; s > 0; s >>= 1) { if (t < s) red[t] += red[t + s]; __syncthreads(); }
    const float mean = red[0] * (1.f / 256.f);
    __syncthreads();
    const float d = v - mean;
    red[t] = d * d; __syncthreads();
    for (int s = 128; s > 0; s >>= 1) { if (t < s) red[t] += red[t + s]; __syncthreads(); }
    const float var = red[0] * (1.f / 256.f);
    const float y = d * rsqrtf(var + 1e-5f) * g[t] + bta[t];
    if (outF) outF[row * D_ + t] = y;
    if (outB) outB[row * D_ + t] = __float2bfloat16(y);
    if (out2) out2[row * D_ + t] = y;
}

__global__ void scatterlocal_k(const float* tail, bf* Slocalh, float* Sacc) {
    const int i = blockIdx.x; const int t = threadIdx.x;
    const int n = i & (N_ - 1), b = i >> 9;
    float v = 0.f;
    if (n >= N_ - LW_) {
        v = tail[((long long)(b * LW_ + (n - (N_ - LW_)))) * D_ + t];
        Sacc[(long long)i * D_ + t] += v;
    }
    Slocalh[(long long)i * D_ + t] = __float2bfloat16(v);
}

__global__ void zero4_k(float4* p) {
    p[(long long)blockIdx.x * 256 + threadIdx.x] = make_float4(0.f, 0.f, 0.f, 0.f);
}

__global__ __launch_bounds__(256) void pred_k(const float* F, const float* pw, const float* pb,
                                              float* out) {
    const int tid = threadIdx.x;
    const int wave = tid >> 6, lane = tid & 63;
    const long long row = (long long)blockIdx.x * 4 + wave;
    const float* fp = F + row * D_ + lane * 4;
    float s = 0.f;
    #pragma unroll
    for (int j = 0; j < 4; j++) s += fp[j] * pw[lane * 4 + j];
    #pragma unroll
    for (int off = 32; off > 0; off >>= 1) s += __shfl_down(s, off);
    if (lane == 0) {
        float p = 1.f / (1.f + __expf(-(s + pb[0])));
        out[row] = p;
    }
}

// ---------------------------------------------------------------------------
static void gemm2(hipStream_t st, const bf* Aq, const bf* Akv,
                  const bf* W, const float* bias, float* Cf, bf* Cb, float* Cacc,
                  int M, int K, int Onum,
                  int rowsPerA, long long aBatch, int aRstride, long long aKMul,
                  long long aZ, long long wZ, long long cZ, int Z,
                  int qkv, int flags, int splitKc,
                  bf* Qd, bf* Kd, bf* Vd, int Lseq, int Lvt)
{
    dim3 g(Onum / 128, (M + 127) / 128, Z), blk(256, 1, 1);
    gemm2_k<<<g, blk, 0, st>>>(Aq, Akv, W, bias, Cf, Cb, Cacc, M, K, Onum,
                               rowsPerA, aBatch, aRstride, aKMul,
                               aZ, wZ, cZ, qkv, flags, splitKc,
                               Qd, Kd, Vd, Lseq, Lvt);
}

static void gemm64(hipStream_t st, const bf* A, const bf* W, const float* bias,
                   float* Cf, bf* Cb, float* Cacc, int M, int K, int Onum,
                   int rowsPerA, long long aBatch, int aRstride, long long aKMul,
                   long long aZ, long long wZ, long long cZ, int Z, int flags)
{
    dim3 g(Onum / 64, (M + 63) / 64, Z), blk(256, 1, 1);
    gemm64_k<<<g, blk, 0, st>>>(A, W, bias, Cf, Cb, Cacc, M, K, Onum,
                                rowsPerA, aBatch, aRstride, aKMul,
                                aZ, wZ, cZ, flags);
}

static void egemm(hipStream_t st, const bf* A, const bf* W, const float* bias,
                  float* Cf, bf* Cb, float* Cacc, int M, int Onum,
                  int rowsPerA, long long aBatch, int aRstride, long long aKMul,
                  int flags)
{
    dim3 g(((M + 127) / 128) * (Onum / 64), 1, 1), blk(256, 1, 1);
    egemm_k<8><<<g, blk, 0, st>>>(A, W, bias, Cf, Cb, Cacc, M, Onum,
                                  rowsPerA, aBatch, aRstride, aKMul, flags);
}

static void dqkv(hipStream_t st, const bf* Aq, const bf* Akv,
                 const bf* W, const float* bias, int M,
                 int rowsPerA, long long aBatch, int aRstride, long long aKMul,
                 bf* Qd, bf* Kd, bf* Vd, int Lseq, int Lvt)
{
    dim3 g(((M + 127) / 128) * 12, 1, 1), blk(256, 1, 1);
    if (Lseq == 512 && (M & 127) == 0)
        dgemm_k<9, 8><<<g, blk, 0, st>>>(Aq, Akv, W, bias, M,
                                         rowsPerA, aBatch, aRstride, aKMul,
                                         Qd, Kd, Vd, Lseq, Lvt);
    else
        dgemm_k<0, 8><<<g, blk, 0, st>>>(Aq, Akv, W, bias, M,
                                         rowsPerA, aBatch, aRstride, aKMul,
                                         Qd, Kd, Vd, Lseq, Lvt);
}

extern "C" void kernel_launch(void* const* d_in, const int* in_sizes, int n_in,
                              void* d_out, int out_size, void* d_ws, size_t ws_size,
                              hipStream_t stream)
{
    const int* qi  = (const int*)d_in[0];
    const int* ri  = (const int*)d_in[1];
    const int* qry = (const int*)d_in[2];
    const float* Memb = (const float*)d_in[3];
    const float* Eemb = (const float*)d_in[4];
    const float* Pp   = (const float*)d_in[5];
    const float* ainw = (const float*)d_in[6];
    const float* ainb = (const float*)d_in[7];
    const float* aoutw= (const float*)d_in[8];
    const float* aoutb= (const float*)d_in[9];
    const float* scw  = (const float*)d_in[10];
    const float* spw  = (const float*)d_in[11];
    const float* spb  = (const float*)d_in[12];
    const float* stew = (const float*)d_in[13];
    const float* steb = (const float*)d_in[14];
    const float* fw1  = (const float*)d_in[15];
    const float* fb1  = (const float*)d_in[16];
    const float* fw2  = (const float*)d_in[17];
    const float* fb2  = (const float*)d_in[18];
    const float* l1g  = (const float*)d_in[19];
    const float* l1b  = (const float*)d_in[20];
    const float* l2g  = (const float*)d_in[21];
    const float* l2b  = (const float*)d_in[22];
    const float* pw   = (const float*)d_in[23];
    const float* pb   = (const float*)d_in[24];
    float* out = (float*)d_out;
    float* outW = out + B_ * N_;

    const size_t BND = (size_t)B_ * N_ * D_;   // 4,194,304
    float* ws = (float*)d_ws;
    float* b10 = ws;                 // accumulator f32
    float* b0  = ws + 1 * BND;       // M f32 / tail scratch / FFN-out f32
    float* b1  = ws + 2 * BND;       // E f32 / ln2-out f32
    float* b8  = ws + 3 * BND;       // S_sg f32 / attn0 stats (float2)
    float* b9  = ws + 4 * BND;       // S_glob f32
    float* hp  = ws + 5 * BND;       // bf16 region start
    bf* b0h  = (bf*)(hp + 0 * (BND / 2));   // M bf16
    bf* b1h  = (bf*)(hp + 1 * (BND / 2));   // E bf16 / G bf16
    bf* b2h  = (bf*)(hp + 2 * (BND / 2));   // S_base bf16
    bf* b7h  = (bf*)(hp + 3 * (BND / 2));   // S_local bf16
    bf* b8h  = (bf*)(hp + 4 * (BND / 2));
    bf* b9h  = (bf*)(hp + 5 * (BND / 2));
    bf* b10h = (bf*)(hp + 6 * (BND / 2));
    bf* b11h = (bf*)(hp + 7 * (BND / 2));   // S_sg-pre / FFN hidden bf16
    bf* Qb   = (bf*)(hp + 8 * (BND / 2));
    bf* Kb   = (bf*)(hp + 9 * (BND / 2));
    bf* Vtb  = (bf*)(hp + 10 * (BND / 2));
    bf* Ob   = (bf*)(hp + 11 * (BND / 2));  // attn out bf16 (BH,L,32)
    bf* BNNb = (bf*)(hp + 12 * (BND / 2));  // (B,N,N) bf16
    float* Ttab = hp + 12 * (BND / 2) + BND;        // (2048,256) f32
    bf* SWb  = (bf*)(Ttab + 2048 * 256);            // (2048,2048) bf16
    bf* Wb   = SWb + (size_t)2048 * 2048;           // weights bf16
    bf* ainwB = Wb;
    bf* aoutwB = ainwB + 6 * 768 * 256;
    bf* spwB  = aoutwB + 6 * 256 * 256;
    bf* stewB = spwB + 256 * 2048;
    bf* fw1B  = stewB + 256 * 512;
    bf* fw2B  = fw1B + 256 * 256;
    const int BNrows = B_ * N_;               // 16384
    const int BH = B_ * H_;                   // 256
    const long long OBAT = 8LL * N_ * HD_;    // O batch stride (b) full attns
    const long long OBATL = 8LL * LW_ * HD_;  // O batch stride attn1

    // --- weight conversions (bf16) ---
    conv_k<<<(6*768*256 + 255)/256, 256, 0, stream>>>(ainw, ainwB, 6*768*256);
    conv_k<<<(6*256*256 + 255)/256, 256, 0, stream>>>(aoutw, aoutwB, 6*256*256);
    conv_k<<<(256*2048 + 255)/256, 256, 0, stream>>>(spw, spwB, 256*2048);
    conv_k<<<(256*512 + 255)/256, 256, 0, stream>>>(stew, stewB, 256*512);
    conv_k<<<(256*256 + 255)/256, 256, 0, stream>>>(fw1, fw1B, 256*256);
    conv_k<<<(256*256 + 255)/256, 256, 0, stream>>>(fw2, fw2B, 256*256);

    // --- skill table: Ttab = softmax(scw) @ spw^T   (splitK=8, f32 atomics) ---
    rowsoftmax_k<<<2048, 256, 0, stream>>>(scw, SWb);
    zero4_k<<<(2048 * 256) / 1024, 256, 0, stream>>>((float4*)Ttab);
    gemm2(stream, SWb, SWb, spwB, nullptr, Ttab, nullptr, nullptr, 2048, 2048, 256,
          2048, 0, 2048, 1, 0, 0, 0, 8, 0, 4, 256, nullptr, nullptr, nullptr, 0, 0);

    // --- embeddings ---
    embed_k<<<BNrows, 256, 0, stream>>>(qi, ri, qry, Memb, Eemb, Pp, b0, b1, b0h, b1h);

    // --- attn 0: q=E, kv=M, causal, head-mean -> outW ---
    dqkv(stream, b1h, b0h, ainwB + 0, ainb + 0, BNrows,
         BNrows, 0, 256, 1, Qb, Kb, Vtb, N_, N_);
    fattn_k<1, 1><<<dim3(BH, 8), 256, 0, stream>>>(Qb, Kb, Vtb, Ob, (float2*)b8, N_, N_);
    meanp_k<<<dim3(B_, 32), 256, 0, stream>>>(Qb, Kb, (const float2*)b8, outW);
    egemm(stream, Ob, aoutwB + 0, aoutb + 0, b10, nullptr, nullptr, BNrows, 256,
          N_, OBAT, HD_, N_, 0);
    // S_base = LN1(proj + M + E)
    ln_k<<<BNrows, 256, 0, stream>>>(b10, b0, b1, l1g, l1b, nullptr, b2h, b10);

    // --- attn 1 (local, LW=25, causal) on S_base tail ---
    dqkv(stream, b2h + (size_t)(N_ - LW_) * D_, b2h + (size_t)(N_ - LW_) * D_,
         ainwB + 1 * 196608, ainb + 768, B_ * LW_,
         LW_, (long long)N_ * D_, 256, 1, Qb, Kb, Vtb, LW_, 32);
    attn5_k<0, 2><<<dim3(BH, 1), 256, 0, stream>>>(Qb, Kb, Vtb, Ob, nullptr, LW_, 32, 1, 1);
    gemm64(stream, Ob, aoutwB + 1 * 65536, aoutb + 256, b0, nullptr, nullptr, B_ * LW_,
           256, 256, LW_, OBATL, HD_, LW_, 0, 0, 0, 1, 0);
    scatterlocal_k<<<BNrows, 256, 0, stream>>>(b0, b7h, b10);

    // --- skill group path ---
    gather_k<<<BNrows, 256, 0, stream>>>(qi, Ttab, spb, b1h);   // G bf16
    gemm64(stream, b2h, b1h, nullptr, nullptr, BNNb, nullptr, N_, 256, N_,
           N_, 0, 256, 1, (long long)N_ * D_, (long long)N_ * D_, (long long)N_ * N_,
           B_, 0);
    gemm64(stream, BNNb, stewB, steb, nullptr, b11h, nullptr, BNrows, 512, 256,
           BNrows, 0, 512, 1, 0, 0, 0, 1, 0);
    dqkv(stream, b11h, b11h, ainwB + 2 * 196608, ainb + 2 * 768, BNrows,
         BNrows, 0, 256, 1, Qb, Kb, Vtb, N_, N_);
    fattn_k<0, 0><<<dim3(BH, 8), 256, 0, stream>>>(Qb, Kb, Vtb, Ob, nullptr, N_, N_);
    egemm(stream, Ob, aoutwB + 2 * 65536, aoutb + 2 * 256, b8, b8h, b10, BNrows, 256,
          N_, OBAT, HD_, N_, 0);

    // --- attn 3: self on S_base, causal -> S_glob (+acc) ---
    dqkv(stream, b2h, b2h, ainwB + 3 * 196608, ainb + 3 * 768, BNrows,
         BNrows, 0, 256, 1, Qb, Kb, Vtb, N_, N_);
    fattn_k<1, 0><<<dim3(BH, 8), 256, 0, stream>>>(Qb, Kb, Vtb, Ob, nullptr, N_, N_);
    egemm(stream, Ob, aoutwB + 3 * 65536, aoutb + 3 * 256, b9, b9h, b10, BNrows, 256,
          N_, OBAT, HD_, N_, 0);

    // --- attn 4: q=S_base, kv=S_local -> accumulate ---
    dqkv(stream, b2h, b7h, ainwB + 4 * 196608, ainb + 4 * 768, BNrows,
         BNrows, 0, 256, 1, Qb, Kb, Vtb, N_, N_);
    fattn_k<0, 0><<<dim3(BH, 8), 256, 0, stream>>>(Qb, Kb, Vtb, Ob, nullptr, N_, N_);
    egemm(stream, Ob, aoutwB + 4 * 65536, aoutb + 4 * 256, b10, nullptr, nullptr, BNrows,
          256, N_, OBAT, HD_, N_, 2);

    // --- attn 5: q=S_sg, kv=S_glob -> accumulate + bf16 shadow ---
    dqkv(stream, b8h, b9h, ainwB + 5 * 196608, ainb + 5 * 768, BNrows,
         BNrows, 0, 256, 1, Qb, Kb, Vtb, N_, N_);
    fattn_k<0, 0><<<dim3(BH, 8), 256, 0, stream>>>(Qb, Kb, Vtb, Ob, nullptr, N_, N_);
    egemm(stream, Ob, aoutwB + 5 * 65536, aoutb + 5 * 256, b10, b10h, nullptr, BNrows,
          256, N_, OBAT, HD_, N_, 2);

    // --- FFN + LN2 + prediction ---
    egemm(stream, b10h, fw1B, fb1, nullptr, b11h, nullptr, BNrows, 256,
          BNrows, 0, 256, 1, 1);
    egemm(stream, b11h, fw2B, fb2, b0, nullptr, nullptr, BNrows, 256,
          BNrows, 0, 256, 1, 0);
    ln_k<<<BNrows, 256, 0, stream>>>(b0, b10, nullptr, l2g, l2b, b1, nullptr, nullptr);
    pred_k<<<BNrows / 4, 256, 0, stream>>>(b1, pw, pb, out);
}

// Round 14
// 782.099 us; speedup vs baseline: 1.0604x; 1.0604x over previous
//
#include <hip/hip_runtime.h>
#include <hip/hip_bf16.h>

#define B_  32
#define N_  512
#define D_  256
#define H_  8
#define HD_ 32
#define LW_ 25

typedef __hip_bfloat16 bf;
typedef __attribute__((ext_vector_type(8))) short short8;
typedef __attribute__((ext_vector_type(4))) float f32x4;

__device__ __forceinline__ void gload16(const void* g, void* l) {
    __builtin_amdgcn_global_load_lds(
        (const __attribute__((address_space(1))) unsigned int*)g,
        (__attribute__((address_space(3))) unsigned int*)l, 16, 0, 0);
}

// 1/sqrt(32) * log2(e): folded into Q so attention uses raw exp2
#define QSC 0.2550349f

// ---------------------------------------------------------------------------
// MFMA bf16 GEMM (LDS-staged, 128x128 tile): used ONLY for the splitK
// skill-table GEMM (K=2048, atomics) where the big tile amortizes best.
// flags: 1=relu, 2=accumulate into Cf, 4=atomicAdd (splitK).
// ---------------------------------------------------------------------------
__global__ __launch_bounds__(256) void gemm2_k(
    const bf* Aq, const bf* Akv, const bf* W, const float* bias,
    float* Cf, bf* Cb, float* Cacc,
    int M, int K, int Onum,
    int rowsPerA, long long aBatch, int aRstride, long long aKMul,
    long long aZ, long long wZ, long long cZ,
    int qkvmode, int flags, int splitKc,
    bf* Qd, bf* Kd, bf* Vd, int Lseq, int Lvt)
{
    __shared__ __align__(16) bf As[128 * 32];
    __shared__ __align__(16) bf Bs[128 * 32];
    const int tid = threadIdx.x;
    const int o0 = blockIdx.x * 128;
    const int m0 = blockIdx.y * 128;
    const int z  = blockIdx.z;
    const bf* A = (qkvmode && o0 >= 256) ? Akv : Aq;
    const bf* Wp = W;
    int kStart = 0, kEnd = K;
    if (splitKc > 0) {
        kStart = z * splitKc;
        kEnd   = min(K, kStart + splitKc);
    } else {
        A  += (long long)z * aZ;
        Wp += (long long)z * wZ;
        if (Cf) Cf += (long long)z * cZ;
        if (Cb) Cb += (long long)z * cZ;
    }

    const int w = tid >> 6, lane = tid & 63;
    const int col = lane & 15, quad = lane >> 4;
    const int wm = (w & 1) * 64;
    const int wn = (w >> 1) * 64;

    const int sidx0 = tid, sidx1 = tid + 256;
    long long arow0, arow1;
    {
        int m = m0 + (sidx0 >> 2);
        arow0 = (long long)(m / rowsPerA) * aBatch + (long long)(m % rowsPerA) * aRstride;
        m = m0 + (sidx1 >> 2);
        arow1 = (long long)(m / rowsPerA) * aBatch + (long long)(m % rowsPerA) * aRstride;
    }
    const long long wrow0 = (long long)(o0 + (sidx0 >> 2)) * K;
    const long long wrow1 = (long long)(o0 + (sidx1 >> 2)) * K;
    const int ac0 = (sidx0 & 3) * 8, ac1 = (sidx1 & 3) * 8;

    f32x4 acc[4][4];
    #pragma unroll
    for (int mt = 0; mt < 4; mt++)
        #pragma unroll
        for (int nt = 0; nt < 4; nt++)
            acc[mt][nt] = (f32x4)0.f;

    for (int k0 = kStart; k0 < kEnd; k0 += 32) {
        const long long ka = (long long)k0 * aKMul;
        gload16(A + arow0 + ka + ac0, As + sidx0 * 8);
        gload16(A + arow1 + ka + ac1, As + sidx1 * 8);
        gload16(Wp + wrow0 + k0 + ac0, Bs + sidx0 * 8);
        gload16(Wp + wrow1 + k0 + ac1, Bs + sidx1 * 8);
        __syncthreads();
        short8 af[4], bfr[4];
        #pragma unroll
        for (int mt = 0; mt < 4; mt++)
            af[mt] = *(const short8*)(As + (wm + mt * 16 + col) * 32 + quad * 8);
        #pragma unroll
        for (int nt = 0; nt < 4; nt++)
            bfr[nt] = *(const short8*)(Bs + (wn + nt * 16 + col) * 32 + quad * 8);
        #pragma unroll
        for (int mt = 0; mt < 4; mt++)
            #pragma unroll
            for (int nt = 0; nt < 4; nt++)
                acc[mt][nt] = __builtin_amdgcn_mfma_f32_16x16x32_bf16(
                    af[mt], bfr[nt], acc[mt][nt], 0, 0, 0);
        __syncthreads();
    }

    #pragma unroll
    for (int mt = 0; mt < 4; mt++) {
        #pragma unroll
        for (int nt = 0; nt < 4; nt++) {
            const int o = o0 + wn + nt * 16 + col;
            #pragma unroll
            for (int r = 0; r < 4; r++) {
                const int m = m0 + wm + mt * 16 + quad * 4 + r;
                if (m >= M) continue;
                float v = acc[mt][nt][r];
                if (bias) v += bias[o];
                if (flags & 1) v = fmaxf(v, 0.f);
                if (flags & 4) {
                    atomicAdd(Cf + (long long)m * Onum + o, v);
                } else {
                    long long ci = (long long)m * Onum + o;
                    if (flags & 2) v += Cf[ci];
                    if (Cf) Cf[ci] = v;
                    if (Cb) Cb[ci] = __float2bfloat16(v);
                    if (Cacc) Cacc[ci] += v;
                }
            }
        }
    }
}

// ---------------------------------------------------------------------------
// MFMA bf16 GEMM (LDS-staged, 64x64 tile): occupancy-oriented variant for
// skinny outputs (O=256/512, K=256/512, M large). grid = (O/64, ceil(M/64), Z)
// gives 4-8 blocks/CU so the per-K-step barrier drains overlap across blocks.
// 4 waves x (32x32); same generalized A addressing + epilogue flags.
// ---------------------------------------------------------------------------
__global__ __launch_bounds__(256) void gemm64_k(
    const bf* A, const bf* W, const float* bias,
    float* Cf, bf* Cb, float* Cacc,
    int M, int K, int Onum,
    int rowsPerA, long long aBatch, int aRstride, long long aKMul,
    long long aZ, long long wZ, long long cZ, int flags)
{
    __shared__ __align__(16) bf As[64 * 32];
    __shared__ __align__(16) bf Bs[64 * 32];
    const int tid = threadIdx.x;
    const int o0 = blockIdx.x * 64;
    const int m0 = blockIdx.y * 64;
    const int z  = blockIdx.z;
    A += (long long)z * aZ;
    W += (long long)z * wZ;
    if (Cf)   Cf   += (long long)z * cZ;
    if (Cb)   Cb   += (long long)z * cZ;
    if (Cacc) Cacc += (long long)z * cZ;

    const int w = tid >> 6, lane = tid & 63;
    const int col = lane & 15, quad = lane >> 4;
    const int wm = (w & 1) * 32;
    const int wn = (w >> 1) * 32;

    const int srow = tid >> 2;          // 0..63
    const int sac  = (tid & 3) * 8;
    long long arow;
    {
        const int m = m0 + srow;
        arow = (long long)(m / rowsPerA) * aBatch
             + (long long)(m % rowsPerA) * aRstride;
    }
    const long long wrow = (long long)(o0 + srow) * K;

    f32x4 acc[2][2];
    acc[0][0] = (f32x4)0.f; acc[0][1] = (f32x4)0.f;
    acc[1][0] = (f32x4)0.f; acc[1][1] = (f32x4)0.f;

    for (int k0 = 0; k0 < K; k0 += 32) {
        gload16(A + arow + (long long)k0 * aKMul + sac, As + tid * 8);
        gload16(W + wrow + k0 + sac, Bs + tid * 8);
        __syncthreads();
        short8 af[2], bfr[2];
        #pragma unroll
        for (int mt = 0; mt < 2; mt++)
            af[mt] = *(const short8*)(As + (wm + mt * 16 + col) * 32 + quad * 8);
        #pragma unroll
        for (int nt = 0; nt < 2; nt++)
            bfr[nt] = *(const short8*)(Bs + (wn + nt * 16 + col) * 32 + quad * 8);
        #pragma unroll
        for (int mt = 0; mt < 2; mt++)
            #pragma unroll
            for (int nt = 0; nt < 2; nt++)
                acc[mt][nt] = __builtin_amdgcn_mfma_f32_16x16x32_bf16(
                    af[mt], bfr[nt], acc[mt][nt], 0, 0, 0);
        __syncthreads();
    }

    #pragma unroll
    for (int mt = 0; mt < 2; mt++) {
        #pragma unroll
        for (int nt = 0; nt < 2; nt++) {
            const int o = o0 + wn + nt * 16 + col;
            #pragma unroll
            for (int r = 0; r < 4; r++) {
                const int m = m0 + wm + mt * 16 + quad * 4 + r;
                if (m >= M) continue;
                float v = acc[mt][nt][r];
                if (bias) v += bias[o];
                if (flags & 1) v = fmaxf(v, 0.f);
                if (flags & 4) {
                    atomicAdd(Cf + (long long)m * Onum + o, v);
                } else {
                    long long ci = (long long)m * Onum + o;
                    if (flags & 2) v += Cf[ci];
                    if (Cf) Cf[ci] = v;
                    if (Cb) Cb[ci] = __float2bfloat16(v);
                    if (Cacc) Cacc[ci] += v;
                }
            }
        }
    }
}

// ---------------------------------------------------------------------------
// QKV GEMM v3: W tile (64o x 256k = 32KB) staged ONCE into padded LDS
// ([64][264], 2-way bank access on b128 reads = free); ALL 16 A fragments
// issued up-front so their global latency hides under staging + barrier.
// K-loop is then registers + LDS only (no global latency on critical path).
// XCD-aware 1-D grid decode (bijective when nmb%8==0). LP2>0: pow2 Lseq =>
// shift/mask addressing, V^T stores packed as 8B ushort4.
// Block = 128m x 64o, 4 waves on m; K = KC*32 (compile-time).
// ---------------------------------------------------------------------------
template<int LP2, int KC>
__global__ __launch_bounds__(256) void dgemm_k(
    const bf* Aq, const bf* Akv, const bf* W, const float* bias,
    int M,
    int rowsPerA, long long aBatch, int aRstride, long long aKMul,
    bf* Qd, bf* Kd, bf* Vd, int Lseq, int Lvt)
{
    __shared__ __align__(16) bf Ws[64][264];   // padded: row stride 528B
    const int tid = threadIdx.x;
    const int w = tid >> 6, lane = tid & 63;
    const int col = lane & 15, quad = lane >> 4;
    const int nmb = gridDim.x / 12;
    int ob, mb;
    if ((nmb & 7) == 0) {
        const int xcd = blockIdx.x & 7;
        const int q = blockIdx.x >> 3;
        mb = xcd + 8 * (q / 12);
        ob = q % 12;
    } else {
        ob = blockIdx.x % 12;
        mb = blockIdx.x / 12;
    }
    const int o0 = ob * 64;
    const int m0 = mb * 128;
    const bf* A = (o0 >= 256) ? Akv : Aq;
    const int K = KC * 32;

    const bf* aP[2];
    #pragma unroll
    for (int mt = 0; mt < 2; mt++) {
        const int m = m0 + w * 32 + mt * 16 + col;
        aP[mt] = A + (long long)(m / rowsPerA) * aBatch
               + (long long)(m % rowsPerA) * aRstride + quad * 8;
    }

    // ---- issue ALL A fragment loads (latency overlaps staging+barrier) ----
    short8 afr[2][KC];
    #pragma unroll
    for (int kc = 0; kc < KC; kc++) {
        afr[0][kc] = *(const short8*)(aP[0] + (long long)kc * 32 * aKMul);
        afr[1][kc] = *(const short8*)(aP[1] + (long long)kc * 32 * aKMul);
    }

    // ---- stage W tile into padded LDS (coalesced 512B rows) ----
    {
        const int srow = tid >> 5;          // 0..7
        const int sk   = (tid & 31) * 8;    // 0..248
        #pragma unroll
        for (int rd = 0; rd < 8; rd++) {
            const int row = rd * 8 + srow;
            const short8 wv = *(const short8*)(W + (long long)(o0 + row) * K + sk);
            *(short8*)(&Ws[row][sk]) = wv;
        }
    }
    __syncthreads();

    f32x4 acc[2][4];
    #pragma unroll
    for (int mt = 0; mt < 2; mt++)
        #pragma unroll
        for (int ot = 0; ot < 4; ot++)
            acc[mt][ot] = (f32x4)0.f;

    #pragma unroll
    for (int kc = 0; kc < KC; kc++) {
        #pragma unroll
        for (int ot = 0; ot < 4; ot++) {
            const short8 bfg = *(const short8*)(&Ws[ot * 16 + col][kc * 32 + quad * 8]);
            acc[0][ot] = __builtin_amdgcn_mfma_f32_16x16x32_bf16(
                afr[0][kc], bfg, acc[0][ot], 0, 0, 0);
            acc[1][ot] = __builtin_amdgcn_mfma_f32_16x16x32_bf16(
                afr[1][kc], bfg, acc[1][ot], 0, 0, 0);
        }
    }

    const int which = o0 >> 8;   // block-uniform: 0=Q, 1=K, 2=V
    #pragma unroll
    for (int mt = 0; mt < 2; mt++) {
        const int mb4 = m0 + w * 32 + mt * 16 + quad * 4;
        #pragma unroll
        for (int ot = 0; ot < 4; ot++) {
            const int o  = o0 + ot * 16 + col;
            const int j2 = o & 31;
            const int hh = (o >> 5) & 7;
            if (LP2 > 0) {
                const int bb  = mb4 >> LP2;
                const int nn0 = mb4 & ((1 << LP2) - 1);
                const int bh  = bb * H_ + hh;
                float v0 = acc[mt][ot][0], v1 = acc[mt][ot][1],
                      v2 = acc[mt][ot][2], v3 = acc[mt][ot][3];
                if (bias) {
                    const float bv = bias[o];
                    v0 += bv; v1 += bv; v2 += bv; v3 += bv;
                }
                if (which == 0) {
                    bf* q = Qd + ((size_t)bh * Lseq + nn0) * HD_ + j2;
                    q[0]      = __float2bfloat16(v0 * QSC);
                    q[HD_]    = __float2bfloat16(v1 * QSC);
                    q[2*HD_]  = __float2bfloat16(v2 * QSC);
                    q[3*HD_]  = __float2bfloat16(v3 * QSC);
                } else if (which == 1) {
                    bf* kd = Kd + ((size_t)bh * Lseq + nn0) * HD_ + j2;
                    kd[0]     = __float2bfloat16(v0);
                    kd[HD_]   = __float2bfloat16(v1);
                    kd[2*HD_] = __float2bfloat16(v2);
                    kd[3*HD_] = __float2bfloat16(v3);
                } else {
                    __align__(8) bf pk[4];
                    pk[0] = __float2bfloat16(v0);
                    pk[1] = __float2bfloat16(v1);
                    pk[2] = __float2bfloat16(v2);
                    pk[3] = __float2bfloat16(v3);
                    *(ushort4*)(Vd + ((size_t)bh * HD_ + j2) * Lvt + nn0) =
                        *(const ushort4*)pk;
                }
            } else {
                #pragma unroll
                for (int r = 0; r < 4; r++) {
                    const int m = mb4 + r;
                    if (m >= M) continue;
                    float v = acc[mt][ot][r];
                    if (bias) v += bias[o];
                    const int bb = m / Lseq, nn = m % Lseq;
                    const int bh = bb * H_ + hh;
                    if (which == 0) {
                        Qd[((size_t)bh * Lseq + nn) * HD_ + j2] =
                            __float2bfloat16(v * QSC);
                    } else if (which == 1) {
                        Kd[((size_t)bh * Lseq + nn) * HD_ + j2] = __float2bfloat16(v);
                    } else {
                        Vd[((size_t)bh * HD_ + j2) * Lvt + nn] = __float2bfloat16(v);
                    }
                }
            }
        }
    }
}

// ---------------------------------------------------------------------------
// Per-wave flash attention v4 (64-key chunks): deferred-max + deferred-
// denominator; single-buffer P bounce (wave-private in-order DS); fixed
// per-iteration costs amortized over 2x keys; 4 QK + 4 PV MFMAs/iter.
// K fragments 1-deep rotation prefetch; V loaded at iteration top.
// Peeled chunk 0 (direct m init) and chunk cmax (causal mask, compile-time).
// Causal grids use reversed blockIdx.y (LPT). Requires L % 64 == 0, L >= 128.
// Grid: x = bh, y = q-supertile of 64 rows (4 waves x 16 rows).
// ---------------------------------------------------------------------------
template<int CAUSAL, int STATS>
__global__ __launch_bounds__(256) void fattn_k(
    const bf* __restrict__ Qb, const bf* __restrict__ Kb,
    const bf* __restrict__ Vtb, bf* __restrict__ O,
    float2* __restrict__ St, int L, int Lvt)
{
    __shared__ __align__(16) bf Sh[4][16][72];   // 64 keys + 8 pad (144B rows)
    const int tid = threadIdx.x;
    const int w = tid >> 6, lane = tid & 63;
    const int col = lane & 15, quad = lane >> 4;
    const int bh = blockIdx.x;
    const int yt = CAUSAL ? (int)(gridDim.y - 1 - blockIdx.y) : (int)blockIdx.y;
    const int q0 = yt * 64 + w * 16;
    const int NC = L >> 6;                        // 64-key chunks
    const int cmax = CAUSAL ? min(NC - 1, (q0 + 15) >> 6) : (NC - 1);

    const bf* Qh = Qb  + (size_t)bh * L * HD_;
    const bf* Kh = Kb  + (size_t)bh * L * HD_;
    const bf* Vh = Vtb + (size_t)bh * HD_ * Lvt;

    const short8 aq = *(const short8*)(Qh + (size_t)(q0 + col) * HD_ + quad * 8);

    float m[4];
    float sdp[4] = {0.f, 0.f, 0.f, 0.f};
    f32x4 oacc[2];
    oacc[0] = (f32x4)0.f; oacc[1] = (f32x4)0.f;

    const int qrow = q0 + quad * 4;
    const int kF = 16 * HD_;                      // 16-key stride in K
    const int vHf = 16 * Lvt;                     // hf=1 offset in V^T

    // pointer-stepped streams
    const bf* kP = Kh + (size_t)col * HD_ + quad * 8;   // chunk base (64 keys)
    const bf* vP = Vh + (size_t)col * Lvt + quad * 8;

    // core of one 64-key chunk (fragments already in regs; first/domask are
    // compile-time-foldable per call site)
    auto core = [&](const short8* kf, int c, bool domask, bool first) {
        f32x4 s[4];
        #pragma unroll
        for (int fi = 0; fi < 4; fi++)
            s[fi] = __builtin_amdgcn_mfma_f32_16x16x32_bf16(
                aq, kf[fi], (f32x4)0.f, 0, 0, 0);
        // V fragments: keys kh*32+quad*8, out-dims hf*16+col
        short8 vf00 = *(const short8*)(vP + (long long)c * 64);
        short8 vf01 = *(const short8*)(vP + (long long)c * 64 + vHf);
        short8 vf10 = *(const short8*)(vP + (long long)c * 64 + 32);
        short8 vf11 = *(const short8*)(vP + (long long)c * 64 + 32 + vHf);
        if (domask) {
            #pragma unroll
            for (int fi = 0; fi < 4; fi++) {
                const int key = c * 64 + fi * 16 + col;
                #pragma unroll
                for (int r = 0; r < 4; r++)
                    if (key > qrow + r) s[fi][r] = -1e9f;
            }
        }
        float pml[4];
        #pragma unroll
        for (int r = 0; r < 4; r++)
            pml[r] = fmaxf(fmaxf(s[0][r], s[1][r]), fmaxf(s[2][r], s[3][r]));
        if (first) {
            #pragma unroll
            for (int r = 0; r < 4; r++) {
                float pm = pml[r];
                #pragma unroll
                for (int off = 1; off < 16; off <<= 1)
                    pm = fmaxf(pm, __shfl_xor(pm, off));
                m[r] = pm;
            }
        } else {
            const int okr = (pml[0] <= m[0] + 8.f) && (pml[1] <= m[1] + 8.f)
                         && (pml[2] <= m[2] + 8.f) && (pml[3] <= m[3] + 8.f);
            if (!__all(okr)) {
                #pragma unroll
                for (int r = 0; r < 4; r++) {
                    float pm = pml[r];
                    #pragma unroll
                    for (int off = 1; off < 16; off <<= 1)
                        pm = fmaxf(pm, __shfl_xor(pm, off));
                    const float mn = fmaxf(m[r], pm);
                    const float scl = __builtin_amdgcn_exp2f(m[r] - mn);
                    m[r] = mn;
                    sdp[r] *= scl;
                    oacc[0][r] *= scl;
                    oacc[1][r] *= scl;
                }
            }
        }
        #pragma unroll
        for (int fi = 0; fi < 4; fi++)
            #pragma unroll
            for (int r = 0; r < 4; r++) {
                float e = __builtin_amdgcn_exp2f(s[fi][r] - m[r]);
                sdp[r] += e;
                Sh[w][quad * 4 + r][fi * 16 + col] = __float2bfloat16(e);
            }
        const short8 ap0 = *(const short8*)(&Sh[w][col][quad * 8]);
        const short8 ap1 = *(const short8*)(&Sh[w][col][32 + quad * 8]);
        oacc[0] = __builtin_amdgcn_mfma_f32_16x16x32_bf16(ap0, vf00, oacc[0], 0, 0, 0);
        oacc[0] = __builtin_amdgcn_mfma_f32_16x16x32_bf16(ap1, vf10, oacc[0], 0, 0, 0);
        oacc[1] = __builtin_amdgcn_mfma_f32_16x16x32_bf16(ap0, vf01, oacc[1], 0, 0, 0);
        oacc[1] = __builtin_amdgcn_mfma_f32_16x16x32_bf16(ap1, vf11, oacc[1], 0, 0, 0);
    };

    // preload K chunk 0 + chunk 1 (chunk 1 in-bounds: L >= 128)
    short8 kf[4], kn[4];
    #pragma unroll
    for (int fi = 0; fi < 4; fi++)
        kf[fi] = *(const short8*)(kP + fi * kF);
    kP += 64 * HD_;
    #pragma unroll
    for (int fi = 0; fi < 4; fi++)
        kn[fi] = *(const short8*)(kP + fi * kF);
    kP += 64 * HD_;

    // chunk 0 (peeled): direct m init; mask only when it's also the last
    core(kf, 0, CAUSAL && cmax == 0, true);
    #pragma unroll
    for (int fi = 0; fi < 4; fi++) kf[fi] = kn[fi];

    for (int c = 1; c < cmax; c++) {
        #pragma unroll
        for (int fi = 0; fi < 4; fi++)
            kn[fi] = *(const short8*)(kP + fi * kF);
        kP += 64 * HD_;
        core(kf, c, false, false);
        #pragma unroll
        for (int fi = 0; fi < 4; fi++) kf[fi] = kn[fi];
    }

    if (cmax >= 1)
        core(kf, cmax, CAUSAL != 0, false);

    // ---- final cross-lane denominator reduce (once) ----
    float inv[4];
    #pragma unroll
    for (int r = 0; r < 4; r++) {
        #pragma unroll
        for (int off = 1; off < 16; off <<= 1)
            sdp[r] += __shfl_xor(sdp[r], off);
        inv[r] = 1.f / sdp[r];
    }
    if (STATS && col == 0) {
        #pragma unroll
        for (int r = 0; r < 4; r++)
            St[(size_t)bh * L + q0 + quad * 4 + r] = make_float2(m[r], inv[r]);
    }
    #pragma unroll
    for (int hf = 0; hf < 2; hf++)
        #pragma unroll
        for (int r = 0; r < 4; r++)
            O[((size_t)bh * L + q0 + quad * 4 + r) * HD_ + hf * 16 + col] =
                __float2bfloat16(oacc[hf][r] * inv[r]);
}

// ---------------------------------------------------------------------------
// Head-mean attention probs for attn0 (causal): recompute QK^T per chunk,
// normalize with precomputed per-row (m, 1/sd) stats, accumulate mean over
// 8 heads in registers. No LDS, no barriers. Grid: x = b, y = 16-row q-tile.
// ---------------------------------------------------------------------------
__global__ __launch_bounds__(256) void meanp_k(
    const bf* __restrict__ Qb, const bf* __restrict__ Kb,
    const float2* __restrict__ St, float* __restrict__ meanW)
{
    const int tid = threadIdx.x;
    const int w = tid >> 6, lane = tid & 63;
    const int col = lane & 15, quad = lane >> 4;
    const int b = blockIdx.x;
    const int q0 = blockIdx.y * 16;
    const int cmax = (q0 + 15) >> 5;

    f32x4 mreg[4][2];
    #pragma unroll
    for (int cc = 0; cc < 4; cc++)
        #pragma unroll
        for (int hf = 0; hf < 2; hf++) mreg[cc][hf] = (f32x4)0.f;

    for (int h = 0; h < H_; h++) {
        const int bh = b * H_ + h;
        const bf* Qh = Qb + (size_t)bh * N_ * HD_;
        const bf* Kh = Kb + (size_t)bh * N_ * HD_;
        const short8 aq = *(const short8*)(Qh + (size_t)(q0 + col) * HD_ + quad * 8);
        float mrow[4], irow[4];
        #pragma unroll
        for (int r = 0; r < 4; r++) {
            float2 s2 = St[(size_t)bh * N_ + q0 + quad * 4 + r];
            mrow[r] = s2.x; irow[r] = s2.y;
        }
        #pragma unroll
        for (int cc = 0; cc < 4; cc++) {
            const int c = w + 4 * cc;
            if (c > cmax) continue;          // wave-uniform
            #pragma unroll
            for (int hf = 0; hf < 2; hf++) {
                const int key = c * 32 + hf * 16 + col;
                const short8 kf = *(const short8*)(Kh + (size_t)key * HD_ + quad * 8);
                f32x4 sc = __builtin_amdgcn_mfma_f32_16x16x32_bf16(
                    aq, kf, (f32x4)0.f, 0, 0, 0);
                #pragma unroll
                for (int r = 0; r < 4; r++) {
                    float p = (key > q0 + quad * 4 + r) ? 0.f
                        : __builtin_amdgcn_exp2f(sc[r] - mrow[r]) * irow[r];
                    mreg[cc][hf][r] += p;
                }
            }
        }
    }

    const size_t base = ((size_t)b * N_ + q0) * N_;
    #pragma unroll
    for (int cc = 0; cc < 4; cc++) {
        const int c = w + 4 * cc;
        #pragma unroll
        for (int hf = 0; hf < 2; hf++)
            #pragma unroll
            for (int r = 0; r < 4; r++)
                meanW[base + (size_t)(quad * 4 + r) * N_ + c * 32 + hf * 16 + col]
                    = mreg[cc][hf][r] * 0.125f;
    }
}

// ---------------------------------------------------------------------------
// MFMA attention v5 (kept for tiny local attn1):
// flash-style per-wave softmax + QT q-tiles per block.
// ---------------------------------------------------------------------------
#define SP 520
#define OPS 34

template<int MEAN, int QT>
__global__ __launch_bounds__(256) void attn5_k(
    const bf* Qb, const bf* Kb, const bf* Vtb,
    bf* O, float* meanW, int L, int Lvt, int causal, int nhl)
{
    __shared__ __align__(16) bf Sh[16 * SP];
    __shared__ __align__(16) float redm[2][16][4];
    __shared__ __align__(16) float invRow[16];
    __shared__ __align__(16) float Opart[4][16][OPS];
    const int tid = threadIdx.x;
    const int w = tid >> 6, lane = tid & 63;
    const int col = lane & 15, quad = lane >> 4;
    const int q0 = blockIdx.y * (16 * QT);
    const int bh0 = blockIdx.x * nhl;
    const int NCH = (L + 31) >> 5;
    const int qLast = q0 + (QT - 1) * 16;
    const int cmaxP = causal ? min(NCH - 1, (qLast + 15) >> 5) : (NCH - 1);
    const int nccP = (w <= cmaxP) ? ((cmaxP - w) >> 2) + 1 : 0;

    f32x4 mreg[4][2];
    if (MEAN) {
        #pragma unroll
        for (int cc = 0; cc < 4; cc++)
            #pragma unroll
            for (int hf = 0; hf < 2; hf++) mreg[cc][hf] = (f32x4)0.f;
    }

    for (int hh = 0; hh < nhl; hh++) {
        const int bh = bh0 + hh;
        const bf* Qh = Qb  + (size_t)bh * L * HD_;
        const bf* Kh = Kb  + (size_t)bh * L * HD_;
        const bf* Vh = Vtb + (size_t)bh * HD_ * Lvt;

        short8 aq[QT];
        #pragma unroll
        for (int t = 0; t < QT; t++) {
            aq[t] = (short8)(short)0;
            const int n = q0 + t * 16 + col;
            if (n < L)
                aq[t] = *(const short8*)(Qh + (size_t)n * HD_ + quad * 8);
        }
        short8 kfr[4][2], vfr[4][2];
        #pragma unroll
        for (int cc = 0; cc < 4; cc++) {
            if (cc >= nccP) break;
            const int c = w + 4 * cc;
            #pragma unroll
            for (int hf = 0; hf < 2; hf++) {
                const int key = c * 32 + hf * 16 + col;
                kfr[cc][hf] = (short8)(short)0;
                if (key < L)
                    kfr[cc][hf] = *(const short8*)(Kh + (size_t)key * HD_ + quad * 8);
                vfr[cc][hf] = *(const short8*)(Vh + (size_t)(hf * 16 + col) * Lvt
                                                + c * 32 + quad * 8);
            }
        }

        #pragma unroll
        for (int t = 0; t < QT; t++) {
            const int qt0 = q0 + t * 16;
            const int cmaxT = causal ? min(NCH - 1, (qt0 + 15) >> 5) : (NCH - 1);
            const int nccT = (w <= cmaxT) ? ((cmaxT - w) >> 2) + 1 : 0;

            f32x4 sc[4][2];
            #pragma unroll
            for (int cc = 0; cc < 4; cc++) {
                if (cc >= nccT) break;
                #pragma unroll
                for (int hf = 0; hf < 2; hf++)
                    sc[cc][hf] = __builtin_amdgcn_mfma_f32_16x16x32_bf16(
                        aq[t], kfr[cc][hf], (f32x4)0.f, 0, 0, 0);
            }

            float pm[4] = {-3e38f, -3e38f, -3e38f, -3e38f};
            #pragma unroll
            for (int cc = 0; cc < 4; cc++) {
                if (cc >= nccT) break;
                const int c = w + 4 * cc;
                #pragma unroll
                for (int hf = 0; hf < 2; hf++) {
                    const int key = c * 32 + hf * 16 + col;
                    #pragma unroll
                    for (int r = 0; r < 4; r++) {
                        float v = sc[cc][hf][r];
                        if (causal && key > qt0 + quad * 4 + r) v = -1e9f;
                        sc[cc][hf][r] = v;
                        pm[r] = fmaxf(pm[r], v);
                    }
                }
            }
            #pragma unroll
            for (int r = 0; r < 4; r++)
                #pragma unroll
                for (int off = 1; off < 16; off <<= 1)
                    pm[r] = fmaxf(pm[r], __shfl_xor(pm[r], off));

            float ps[4] = {0.f, 0.f, 0.f, 0.f};
            #pragma unroll
            for (int cc = 0; cc < 4; cc++) {
                if (cc >= nccT) break;
                const int c = w + 4 * cc;
                #pragma unroll
                for (int hf = 0; hf < 2; hf++)
                    #pragma unroll
                    for (int r = 0; r < 4; r++) {
                        float e = __builtin_amdgcn_exp2f(sc[cc][hf][r] - pm[r]);
                        sc[cc][hf][r] = e;
                        ps[r] += e;
                        Sh[(quad * 4 + r) * SP + c * 32 + hf * 16 + col] =
                            __float2bfloat16(e);
                    }
            }
            #pragma unroll
            for (int r = 0; r < 4; r++)
                #pragma unroll
                for (int off = 1; off < 16; off <<= 1)
                    ps[r] += __shfl_xor(ps[r], off);

            f32x4 oacc[2];
            oacc[0] = (f32x4)0.f; oacc[1] = (f32x4)0.f;
            #pragma unroll
            for (int cc = 0; cc < 4; cc++) {
                if (cc >= nccT) break;
                const int c = w + 4 * cc;
                const short8 ap = *(const short8*)(Sh + col * SP + c * 32 + quad * 8);
                #pragma unroll
                for (int hf = 0; hf < 2; hf++)
                    oacc[hf] = __builtin_amdgcn_mfma_f32_16x16x32_bf16(
                        ap, vfr[cc][hf], oacc[hf], 0, 0, 0);
            }

            if (col == 0) {
                #pragma unroll
                for (int r = 0; r < 4; r++) {
                    redm[0][quad * 4 + r][w] = pm[r];
                    redm[1][quad * 4 + r][w] = ps[r];
                }
            }
            __syncthreads();
            float esc[4], inv[4];
            #pragma unroll
            for (int r = 0; r < 4; r++) {
                f32x4 mw = *(const f32x4*)redm[0][quad * 4 + r];
                f32x4 sw = *(const f32x4*)redm[1][quad * 4 + r];
                float M = fmaxf(fmaxf(mw[0], mw[1]), fmaxf(mw[2], mw[3]));
                float T = sw[0] * __builtin_amdgcn_exp2f(mw[0] - M)
                        + sw[1] * __builtin_amdgcn_exp2f(mw[1] - M)
                        + sw[2] * __builtin_amdgcn_exp2f(mw[2] - M)
                        + sw[3] * __builtin_amdgcn_exp2f(mw[3] - M);
                esc[r] = __builtin_amdgcn_exp2f(pm[r] - M);
                inv[r] = 1.f / T;
            }
            if (w == 0 && col == 0) {
                #pragma unroll
                for (int r = 0; r < 4; r++) invRow[quad * 4 + r] = inv[r];
            }
            #pragma unroll
            for (int hf = 0; hf < 2; hf++)
                #pragma unroll
                for (int r = 0; r < 4; r++)
                    Opart[w][quad * 4 + r][hf * 16 + col] = oacc[hf][r] * esc[r];
            if (MEAN) {
                #pragma unroll
                for (int cc = 0; cc < 4; cc++) {
                    if (cc >= nccT) break;
                    #pragma unroll
                    for (int hf = 0; hf < 2; hf++)
                        #pragma unroll
                        for (int r = 0; r < 4; r++)
                            mreg[cc][hf][r] += sc[cc][hf][r] * (esc[r] * inv[r]);
                }
            }
            __syncthreads();

            for (int e = tid; e < 512; e += 256) {
                int row = e >> 5, d = e & 31;
                float v = (Opart[0][row][d] + Opart[1][row][d] +
                           Opart[2][row][d] + Opart[3][row][d]) * invRow[row];
                int n = qt0 + row;
                if (n < L)
                    O[((size_t)bh * L + n) * HD_ + d] = __float2bfloat16(v);
            }
            if (t + 1 < QT || hh + 1 < nhl) __syncthreads();
        }
    }

    if (MEAN) {
        const size_t base = ((size_t)blockIdx.x * N_ + q0) * N_;
        #pragma unroll
        for (int cc = 0; cc < 4; cc++) {
            const int c = w + 4 * cc;
            #pragma unroll
            for (int hf = 0; hf < 2; hf++)
                #pragma unroll
                for (int r = 0; r < 4; r++)
                    meanW[base + (size_t)(quad * 4 + r) * N_ + c * 32 + hf * 16 + col]
                        = mreg[cc][hf][r] * 0.125f;
        }
    }
}

// ---------------------------------------------------------------------------
// Small kernels
// ---------------------------------------------------------------------------
__global__ void conv_k(const float* s, bf* d, int n) {
    int i = blockIdx.x * 256 + threadIdx.x;
    if (i < n) d[i] = __float2bfloat16(s[i]);
}

__global__ __launch_bounds__(256) void rowsoftmax_k(const float* in, bf* out) {
    __shared__ float red[256];
    const long long row = blockIdx.x;
    const int t = threadIdx.x;
    const float* ip = in + row * 2048;
    bf* op = out + row * 2048;
    float m = -3e38f;
    for (int k = t; k < 2048; k += 256) m = fmaxf(m, ip[k]);
    red[t] = m; __syncthreads();
    for (int s = 128; s > 0; s >>= 1) { if (t < s) red[t] = fmaxf(red[t], red[t + s]); __syncthreads(); }
    m = red[0]; __syncthreads();
    float ps = 0.f;
    float ev[8];
    #pragma unroll
    for (int i = 0; i < 8; i++) { ev[i] = __expf(ip[t + i * 256] - m); ps += ev[i]; }
    red[t] = ps; __syncthreads();
    for (int s = 128; s > 0; s >>= 1) { if (t < s) red[t] += red[t + s]; __syncthreads(); }
    const float inv = 1.f / red[0];
    #pragma unroll
    for (int i = 0; i < 8; i++) op[t + i * 256] = __float2bfloat16(ev[i] * inv);
}

__global__ void embed_k(const int* q, const int* r, const int* qry,
                        const float* Memb, const float* Eemb, const float* P,
                        float* M, float* E, bf* Mh, bf* Eh) {
    const int i = blockIdx.x; const int t = threadIdx.x;
    const int n = i & (N_ - 1);
    const int x = q[i] + 2048 * r[i];
    float mv = Memb[(long long)x * D_ + t] + P[(long long)n * D_ + t];
    float evv = Eemb[(long long)qry[i] * D_ + t];
    M[(long long)i * D_ + t] = mv;  Mh[(long long)i * D_ + t] = __float2bfloat16(mv);
    E[(long long)i * D_ + t] = evv; Eh[(long long)i * D_ + t] = __float2bfloat16(evv);
}

__global__ void gather_k(const int* q, const float* T, const float* spb, bf* G) {
    const int i = blockIdx.x; const int t = threadIdx.x;
    G[(long long)i * D_ + t] = __float2bfloat16(T[(long long)q[i] * D_ + t] + spb[t]);
}

__global__ __launch_bounds__(256) void ln_k(const float* xa, const float* xb, const float* xc,
                                            const float* g, const float* bta,
                                            float* outF, bf* outB, float* out2) {
    __shared__ float red[256];
    const long long row = blockIdx.x;
    const int t = threadIdx.x;
    float v = xa[row * D_ + t];
    if (xb) v += xb[row * D_ + t];
    if (xc) v += xc[row * D_ + t];
    red[t] = v; __syncthreads();
    for (int s = 128; s > 0; s >>= 1) { if (t < s) red[t] += red[t + s]; __syncthreads(); }
    const float mean = red[0] * (1.f / 256.f);
    __syncthreads();
    const float d = v - mean;
    red[t] = d * d; __syncthreads();
    for (int s = 128; s > 0; s >>= 1) { if (t < s) red[t] += red[t + s]; __syncthreads(); }
    const float var = red[0] * (1.f / 256.f);
    const float y = d * rsqrtf(var + 1e-5f) * g[t] + bta[t];
    if (outF) outF[row * D_ + t] = y;
    if (outB) outB[row * D_ + t] = __float2bfloat16(y);
    if (out2) out2[row * D_ + t] = y;
}

__global__ void scatterlocal_k(const float* tail, bf* Slocalh, float* Sacc) {
    const int i = blockIdx.x; const int t = threadIdx.x;
    const int n = i & (N_ - 1), b = i >> 9;
    float v = 0.f;
    if (n >= N_ - LW_) {
        v = tail[((long long)(b * LW_ + (n - (N_ - LW_)))) * D_ + t];
        Sacc[(long long)i * D_ + t] += v;
    }
    Slocalh[(long long)i * D_ + t] = __float2bfloat16(v);
}

__global__ void zero4_k(float4* p) {
    p[(long long)blockIdx.x * 256 + threadIdx.x] = make_float4(0.f, 0.f, 0.f, 0.f);
}

__global__ __launch_bounds__(256) void pred_k(const float* F, const float* pw, const float* pb,
                                              float* out) {
    const int tid = threadIdx.x;
    const int wave = tid >> 6, lane = tid & 63;
    const long long row = (long long)blockIdx.x * 4 + wave;
    const float* fp = F + row * D_ + lane * 4;
    float s = 0.f;
    #pragma unroll
    for (int j = 0; j < 4; j++) s += fp[j] * pw[lane * 4 + j];
    #pragma unroll
    for (int off = 32; off > 0; off >>= 1) s += __shfl_down(s, off);
    if (lane == 0) {
        float p = 1.f / (1.f + __expf(-(s + pb[0])));
        out[row] = p;
    }
}

// ---------------------------------------------------------------------------
static void gemm2(hipStream_t st, const bf* Aq, const bf* Akv,
                  const bf* W, const float* bias, float* Cf, bf* Cb, float* Cacc,
                  int M, int K, int Onum,
                  int rowsPerA, long long aBatch, int aRstride, long long aKMul,
                  long long aZ, long long wZ, long long cZ, int Z,
                  int qkv, int flags, int splitKc,
                  bf* Qd, bf* Kd, bf* Vd, int Lseq, int Lvt)
{
    dim3 g(Onum / 128, (M + 127) / 128, Z), blk(256, 1, 1);
    gemm2_k<<<g, blk, 0, st>>>(Aq, Akv, W, bias, Cf, Cb, Cacc, M, K, Onum,
                               rowsPerA, aBatch, aRstride, aKMul,
                               aZ, wZ, cZ, qkv, flags, splitKc,
                               Qd, Kd, Vd, Lseq, Lvt);
}

static void gemm64(hipStream_t st, const bf* A, const bf* W, const float* bias,
                   float* Cf, bf* Cb, float* Cacc, int M, int K, int Onum,
                   int rowsPerA, long long aBatch, int aRstride, long long aKMul,
                   long long aZ, long long wZ, long long cZ, int Z, int flags)
{
    dim3 g(Onum / 64, (M + 63) / 64, Z), blk(256, 1, 1);
    gemm64_k<<<g, blk, 0, st>>>(A, W, bias, Cf, Cb, Cacc, M, K, Onum,
                                rowsPerA, aBatch, aRstride, aKMul,
                                aZ, wZ, cZ, flags);
}

static void dqkv(hipStream_t st, const bf* Aq, const bf* Akv,
                 const bf* W, const float* bias, int M,
                 int rowsPerA, long long aBatch, int aRstride, long long aKMul,
                 bf* Qd, bf* Kd, bf* Vd, int Lseq, int Lvt)
{
    dim3 g(((M + 127) / 128) * 12, 1, 1), blk(256, 1, 1);
    if (Lseq == 512 && (M & 127) == 0)
        dgemm_k<9, 8><<<g, blk, 0, st>>>(Aq, Akv, W, bias, M,
                                         rowsPerA, aBatch, aRstride, aKMul,
                                         Qd, Kd, Vd, Lseq, Lvt);
    else
        dgemm_k<0, 8><<<g, blk, 0, st>>>(Aq, Akv, W, bias, M,
                                         rowsPerA, aBatch, aRstride, aKMul,
                                         Qd, Kd, Vd, Lseq, Lvt);
}

extern "C" void kernel_launch(void* const* d_in, const int* in_sizes, int n_in,
                              void* d_out, int out_size, void* d_ws, size_t ws_size,
                              hipStream_t stream)
{
    const int* qi  = (const int*)d_in[0];
    const int* ri  = (const int*)d_in[1];
    const int* qry = (const int*)d_in[2];
    const float* Memb = (const float*)d_in[3];
    const float* Eemb = (const float*)d_in[4];
    const float* Pp   = (const float*)d_in[5];
    const float* ainw = (const float*)d_in[6];
    const float* ainb = (const float*)d_in[7];
    const float* aoutw= (const float*)d_in[8];
    const float* aoutb= (const float*)d_in[9];
    const float* scw  = (const float*)d_in[10];
    const float* spw  = (const float*)d_in[11];
    const float* spb  = (const float*)d_in[12];
    const float* stew = (const float*)d_in[13];
    const float* steb = (const float*)d_in[14];
    const float* fw1  = (const float*)d_in[15];
    const float* fb1  = (const float*)d_in[16];
    const float* fw2  = (const float*)d_in[17];
    const float* fb2  = (const float*)d_in[18];
    const float* l1g  = (const float*)d_in[19];
    const float* l1b  = (const float*)d_in[20];
    const float* l2g  = (const float*)d_in[21];
    const float* l2b  = (const float*)d_in[22];
    const float* pw   = (const float*)d_in[23];
    const float* pb   = (const float*)d_in[24];
    float* out = (float*)d_out;
    float* outW = out + B_ * N_;

    const size_t BND = (size_t)B_ * N_ * D_;   // 4,194,304
    float* ws = (float*)d_ws;
    float* b10 = ws;                 // accumulator f32
    float* b0  = ws + 1 * BND;       // M f32 / tail scratch / FFN-out f32
    float* b1  = ws + 2 * BND;       // E f32 / ln2-out f32
    float* b8  = ws + 3 * BND;       // S_sg f32 / attn0 stats (float2)
    float* b9  = ws + 4 * BND;       // S_glob f32
    float* hp  = ws + 5 * BND;       // bf16 region start
    bf* b0h  = (bf*)(hp + 0 * (BND / 2));   // M bf16
    bf* b1h  = (bf*)(hp + 1 * (BND / 2));   // E bf16 / G bf16
    bf* b2h  = (bf*)(hp + 2 * (BND / 2));   // S_base bf16
    bf* b7h  = (bf*)(hp + 3 * (BND / 2));   // S_local bf16
    bf* b8h  = (bf*)(hp + 4 * (BND / 2));
    bf* b9h  = (bf*)(hp + 5 * (BND / 2));
    bf* b10h = (bf*)(hp + 6 * (BND / 2));
    bf* b11h = (bf*)(hp + 7 * (BND / 2));   // S_sg-pre / FFN hidden bf16
    bf* Qb   = (bf*)(hp + 8 * (BND / 2));
    bf* Kb   = (bf*)(hp + 9 * (BND / 2));
    bf* Vtb  = (bf*)(hp + 10 * (BND / 2));
    bf* Ob   = (bf*)(hp + 11 * (BND / 2));  // attn out bf16 (BH,L,32)
    bf* BNNb = (bf*)(hp + 12 * (BND / 2));  // (B,N,N) bf16
    float* Ttab = hp + 12 * (BND / 2) + BND;        // (2048,256) f32
    bf* SWb  = (bf*)(Ttab + 2048 * 256);            // (2048,2048) bf16
    bf* Wb   = SWb + (size_t)2048 * 2048;           // weights bf16
    bf* ainwB = Wb;
    bf* aoutwB = ainwB + 6 * 768 * 256;
    bf* spwB  = aoutwB + 6 * 256 * 256;
    bf* stewB = spwB + 256 * 2048;
    bf* fw1B  = stewB + 256 * 512;
    bf* fw2B  = fw1B + 256 * 256;
    const int BNrows = B_ * N_;               // 16384
    const int BH = B_ * H_;                   // 256
    const long long OBAT = 8LL * N_ * HD_;    // O batch stride (b) full attns
    const long long OBATL = 8LL * LW_ * HD_;  // O batch stride attn1

    // --- weight conversions (bf16) ---
    conv_k<<<(6*768*256 + 255)/256, 256, 0, stream>>>(ainw, ainwB, 6*768*256);
    conv_k<<<(6*256*256 + 255)/256, 256, 0, stream>>>(aoutw, aoutwB, 6*256*256);
    conv_k<<<(256*2048 + 255)/256, 256, 0, stream>>>(spw, spwB, 256*2048);
    conv_k<<<(256*512 + 255)/256, 256, 0, stream>>>(stew, stewB, 256*512);
    conv_k<<<(256*256 + 255)/256, 256, 0, stream>>>(fw1, fw1B, 256*256);
    conv_k<<<(256*256 + 255)/256, 256, 0, stream>>>(fw2, fw2B, 256*256);

    // --- skill table: Ttab = softmax(scw) @ spw^T   (splitK=8, f32 atomics) ---
    rowsoftmax_k<<<2048, 256, 0, stream>>>(scw, SWb);
    zero4_k<<<(2048 * 256) / 1024, 256, 0, stream>>>((float4*)Ttab);
    gemm2(stream, SWb, SWb, spwB, nullptr, Ttab, nullptr, nullptr, 2048, 2048, 256,
          2048, 0, 2048, 1, 0, 0, 0, 8, 0, 4, 256, nullptr, nullptr, nullptr, 0, 0);

    // --- embeddings ---
    embed_k<<<BNrows, 256, 0, stream>>>(qi, ri, qry, Memb, Eemb, Pp, b0, b1, b0h, b1h);

    // --- attn 0: q=E, kv=M, causal, head-mean -> outW ---
    dqkv(stream, b1h, b0h, ainwB + 0, ainb + 0, BNrows,
         BNrows, 0, 256, 1, Qb, Kb, Vtb, N_, N_);
    fattn_k<1, 1><<<dim3(BH, 8), 256, 0, stream>>>(Qb, Kb, Vtb, Ob, (float2*)b8, N_, N_);
    meanp_k<<<dim3(B_, 32), 256, 0, stream>>>(Qb, Kb, (const float2*)b8, outW);
    gemm64(stream, Ob, aoutwB + 0, aoutb + 0, b10, nullptr, nullptr, BNrows, 256, 256,
           N_, OBAT, HD_, N_, 0, 0, 0, 1, 0);
    // S_base = LN1(proj + M + E)
    ln_k<<<BNrows, 256, 0, stream>>>(b10, b0, b1, l1g, l1b, nullptr, b2h, b10);

    // --- attn 1 (local, LW=25, causal) on S_base tail ---
    dqkv(stream, b2h + (size_t)(N_ - LW_) * D_, b2h + (size_t)(N_ - LW_) * D_,
         ainwB + 1 * 196608, ainb + 768, B_ * LW_,
         LW_, (long long)N_ * D_, 256, 1, Qb, Kb, Vtb, LW_, 32);
    attn5_k<0, 2><<<dim3(BH, 1), 256, 0, stream>>>(Qb, Kb, Vtb, Ob, nullptr, LW_, 32, 1, 1);
    gemm64(stream, Ob, aoutwB + 1 * 65536, aoutb + 256, b0, nullptr, nullptr, B_ * LW_,
           256, 256, LW_, OBATL, HD_, LW_, 0, 0, 0, 1, 0);
    scatterlocal_k<<<BNrows, 256, 0, stream>>>(b0, b7h, b10);

    // --- skill group path ---
    gather_k<<<BNrows, 256, 0, stream>>>(qi, Ttab, spb, b1h);   // G bf16
    gemm64(stream, b2h, b1h, nullptr, nullptr, BNNb, nullptr, N_, 256, N_,
           N_, 0, 256, 1, (long long)N_ * D_, (long long)N_ * D_, (long long)N_ * N_,
           B_, 0);
    gemm64(stream, BNNb, stewB, steb, nullptr, b11h, nullptr, BNrows, 512, 256,
           BNrows, 0, 512, 1, 0, 0, 0, 1, 0);
    dqkv(stream, b11h, b11h, ainwB + 2 * 196608, ainb + 2 * 768, BNrows,
         BNrows, 0, 256, 1, Qb, Kb, Vtb, N_, N_);
    fattn_k<0, 0><<<dim3(BH, 8), 256, 0, stream>>>(Qb, Kb, Vtb, Ob, nullptr, N_, N_);
    gemm64(stream, Ob, aoutwB + 2 * 65536, aoutb + 2 * 256, b8, b8h, b10, BNrows,
           256, 256, N_, OBAT, HD_, N_, 0, 0, 0, 1, 0);

    // --- attn 3: self on S_base, causal -> S_glob (+acc) ---
    dqkv(stream, b2h, b2h, ainwB + 3 * 196608, ainb + 3 * 768, BNrows,
         BNrows, 0, 256, 1, Qb, Kb, Vtb, N_, N_);
    fattn_k<1, 0><<<dim3(BH, 8), 256, 0, stream>>>(Qb, Kb, Vtb, Ob, nullptr, N_, N_);
    gemm64(stream, Ob, aoutwB + 3 * 65536, aoutb + 3 * 256, b9, b9h, b10, BNrows,
           256, 256, N_, OBAT, HD_, N_, 0, 0, 0, 1, 0);

    // --- attn 4: q=S_base, kv=S_local -> accumulate ---
    dqkv(stream, b2h, b7h, ainwB + 4 * 196608, ainb + 4 * 768, BNrows,
         BNrows, 0, 256, 1, Qb, Kb, Vtb, N_, N_);
    fattn_k<0, 0><<<dim3(BH, 8), 256, 0, stream>>>(Qb, Kb, Vtb, Ob, nullptr, N_, N_);
    gemm64(stream, Ob, aoutwB + 4 * 65536, aoutb + 4 * 256, b10, nullptr, nullptr, BNrows,
           256, 256, N_, OBAT, HD_, N_, 0, 0, 0, 1, 2);

    // --- attn 5: q=S_sg, kv=S_glob -> accumulate + bf16 shadow ---
    dqkv(stream, b8h, b9h, ainwB + 5 * 196608, ainb + 5 * 768, BNrows,
         BNrows, 0, 256, 1, Qb, Kb, Vtb, N_, N_);
    fattn_k<0, 0><<<dim3(BH, 8), 256, 0, stream>>>(Qb, Kb, Vtb, Ob, nullptr, N_, N_);
    gemm64(stream, Ob, aoutwB + 5 * 65536, aoutb + 5 * 256, b10, b10h, nullptr, BNrows,
           256, 256, N_, OBAT, HD_, N_, 0, 0, 0, 1, 2);

    // --- FFN + LN2 + prediction ---
    gemm64(stream, b10h, fw1B, fb1, nullptr, b11h, nullptr, BNrows, 256, 256,
           BNrows, 0, 256, 1, 0, 0, 0, 1, 1);
    gemm64(stream, b11h, fw2B, fb2, b0, nullptr, nullptr, BNrows, 256, 256,
           BNrows, 0, 256, 1, 0, 0, 0, 1, 0);
    ln_k<<<BNrows, 256, 0, stream>>>(b0, b10, nullptr, l2g, l2b, b1, nullptr, nullptr);
    pred_k<<<BNrows / 4, 256, 0, stream>>>(b1, pw, pb, out);
}